// Round 3
// baseline (603.035 us; speedup 1.0000x reference)
//
#include <hip/hip_runtime.h>
#include <hip/hip_fp16.h>
#include <cstdint>

#define NN 50000
#define NQBLK 12500             // k_q blocks: NN*64/256
#define NGBLK 12500             // 4 nodes/block (1 per wave)
#define EPSV 1e-5f

// bucket sort params
#define NPB 128                 // nodes per bucket
#define BSH 7                   // log2(NPB)
#define NBKT 391                // ceil(NN/NPB)
#define CHUNK 4096              // edges per stage-1 block
#define EPT 16                  // edges per thread (CHUNK/256)
#define LDSE 6144               // per-bucket LDS edge capacity

// BN partial-sum spreading: 128 slots x 8 floats per layer (64 cache lines).
// R9/R10: hot-line atomics cost ~120us; spread over 64 lines -> negligible.
#define NSLOT 128

typedef unsigned short ushort_t;
typedef _Float16 half2v __attribute__((ext_vector_type(2)));
typedef unsigned int uintv4 __attribute__((ext_vector_type(4)));   // nontemporal-compatible
typedef float floatv4 __attribute__((ext_vector_type(4)));

// ---------------- stage 1: per-chunk bucket histogram (+ zero BN slots) ----------------
__global__ __launch_bounds__(256) void k_hist1(const int* __restrict__ dst, int E, int nchunk,
                                               int* __restrict__ hist, float* __restrict__ gsumsp) {
    __shared__ int cnt[NBKT];
    int t = threadIdx.x, blk = blockIdx.x;
    if (blk == 0) {
        for (int z = t; z < 5 * NSLOT * 8; z += 256) gsumsp[z] = 0.f;
    }
    for (int b = t; b < NBKT; b += 256) cnt[b] = 0;
    __syncthreads();
    int base = blk * CHUNK;
#pragma unroll
    for (int k = 0; k < EPT; ++k) {
        int e = base + k * 256 + t;
        if (e < E) atomicAdd(&cnt[dst[e] >> BSH], 1);
    }
    __syncthreads();
    for (int b = t; b < NBKT; b += 256) hist[(size_t)b * nchunk + blk] = cnt[b];
}

// ---------------- generic hierarchical exclusive scan ----------------
__global__ __launch_bounds__(256) void k_scanA(const int* __restrict__ in, int n,
                                               int* __restrict__ presum, int* __restrict__ blocksum) {
    __shared__ int lds[256];
    int t = threadIdx.x, g = blockIdx.x * 256 + t;
    int v = (g < n) ? in[g] : 0;
    lds[t] = v;
    __syncthreads();
    for (int off = 1; off < 256; off <<= 1) {
        int x = (t >= off) ? lds[t - off] : 0;
        __syncthreads();
        lds[t] += x;
        __syncthreads();
    }
    if (g < n) presum[g] = lds[t];
    if (t == 255) blocksum[blockIdx.x] = lds[255];
}

__global__ __launch_bounds__(256) void k_scanB(const int* __restrict__ blocksum,
                                               int nb, int* __restrict__ blockoff) {
    __shared__ int lds[256];
    __shared__ int carry_s;
    int t = threadIdx.x;
    if (t == 0) carry_s = 0;
    __syncthreads();
    for (int base = 0; base < nb; base += 256) {
        int g = base + t;
        int v = (g < nb) ? blocksum[g] : 0;
        lds[t] = v;
        __syncthreads();
        for (int off = 1; off < 256; off <<= 1) {
            int x = (t >= off) ? lds[t - off] : 0;
            __syncthreads();
            lds[t] += x;
            __syncthreads();
        }
        if (g < nb) blockoff[g] = lds[t] - v + carry_s;
        __syncthreads();
        if (t == 255) carry_s += lds[255];
        __syncthreads();
    }
}

__global__ __launch_bounds__(256) void k_scanC(const int* __restrict__ presum,
                                               const int* __restrict__ hist,
                                               const int* __restrict__ blockoff,
                                               int n, int nchunk, int* __restrict__ offsT) {
    int g = blockIdx.x * 256 + threadIdx.x;
    if (g < n) {
        int val = presum[g] - hist[g] + blockoff[blockIdx.x];
        int b = g / nchunk;
        int c = g - b * nchunk;
        offsT[(size_t)c * NBKT + b] = val;
    }
}

// ---------------- stage 1: partition edges into buckets ----------------
__global__ __launch_bounds__(256) void k_scatter1(const int* __restrict__ src,
                                                  const int* __restrict__ dst, int E,
                                                  const int* __restrict__ offsT,
                                                  int* __restrict__ ebuf) {
    __shared__ int pos[NBKT];
    int t = threadIdx.x, blk = blockIdx.x;
    for (int b = t; b < NBKT; b += 256) pos[b] = offsT[(size_t)blk * NBKT + b];
    __syncthreads();
    int base = blk * CHUNK;
#pragma unroll
    for (int k = 0; k < EPT; ++k) {
        int e = base + k * 256 + t;
        if (e < E) {
            int d = dst[e];
            int b = d >> BSH;
            int p = atomicAdd(&pos[b], 1);
            ebuf[p] = ((d & (NPB - 1)) << 16) | src[e];
        }
    }
}

// ---------------- stage 2: per-bucket CSR ----------------
__global__ __launch_bounds__(256) void k_bucket_csr(const int* __restrict__ ebuf,
                                                    const int* __restrict__ offsT, int E,
                                                    int* __restrict__ rowstart,
                                                    ushort_t* __restrict__ colsrc) {
    __shared__ int cnt[NPB];
    __shared__ int s[NPB];
    __shared__ int pos2[NPB];
    __shared__ ushort_t lout[LDSE];
    int t = threadIdx.x, b = blockIdx.x;
    int bstart = offsT[b];
    int bend = (b + 1 < NBKT) ? offsT[b + 1] : E;
    int m = bend - bstart;
    if (t < NPB) cnt[t] = 0;
    __syncthreads();
    for (int i = bstart + t; i < bend; i += 256) atomicAdd(&cnt[ebuf[i] >> 16], 1);
    __syncthreads();
    if (t < NPB) s[t] = cnt[t];
    __syncthreads();
    for (int off = 1; off < NPB; off <<= 1) {
        int x = (t < NPB && t >= off) ? s[t - off] : 0;
        __syncthreads();
        if (t < NPB) s[t] += x;
        __syncthreads();
    }
    if (t < NPB) {
        int excl = s[t] - cnt[t];
        int node = b * NPB + t;
        if (node < NN) rowstart[node] = bstart + excl;
        pos2[t] = excl;
    }
    __syncthreads();
    if (m <= LDSE) {
        for (int i = bstart + t; i < bend; i += 256) {
            int v = ebuf[i];
            int p = atomicAdd(&pos2[v >> 16], 1);
            lout[p] = (ushort_t)(v & 0xFFFF);
        }
        __syncthreads();
        for (int i = t; i < m; i += 256) colsrc[bstart + i] = lout[i];
    } else {
        for (int i = bstart + t; i < bend; i += 256) {
            int v = ebuf[i];
            int p = atomicAdd(&pos2[v >> 16], 1);
            colsrc[bstart + p] = (ushort_t)(v & 0xFFFF);
        }
    }
    if (b == NBKT - 1 && t == 0) rowstart[NN] = E;
}

// ---------------- per-layer: node -> (q_s, q_d) in fp16, COLUMN-HALF layout ----------------
// qs/qd stored as [2][NN][32] halves: half h holds cols h*32..h*32+31 (64B per
// node per half). R15: per-XCD gather footprint per half = 3.2MB < 4MB L2.
__global__ __launch_bounds__(256) void k_q(
    const float* __restrict__ pin, int pstride, int c0, int c1, int c2,
    const float* __restrict__ W1l, const float* __restrict__ b1l,
    const float* __restrict__ scale, const float* __restrict__ shift, int use_bn,
    __half* __restrict__ qs, __half* __restrict__ qd) {
    int idx = blockIdx.x * 256 + threadIdx.x;   // v*64 + c
    int v = idx >> 6, c = idx & 63;
    const float* prow = pin + (size_t)v * pstride;
    float p0 = prow[c0], p1 = prow[c1], p2 = prow[c2];
    if (use_bn) {
        p0 = fmaxf(0.f, p0 * scale[0] + shift[0]);
        p1 = fmaxf(0.f, p1 * scale[1] + shift[1]);
        p2 = fmaxf(0.f, p2 * scale[2] + shift[2]);
    }
    float w0 = W1l[0 * 64 + c], w1 = W1l[1 * 64 + c], w2 = W1l[2 * 64 + c];
    float w3 = W1l[3 * 64 + c], w4 = W1l[4 * 64 + c], w5 = W1l[5 * 64 + c];
    size_t o = (size_t)(c >> 5) * NN * 32 + (size_t)v * 32 + (c & 31);
    qs[o] = __float2half(p0 * w0 + p1 * w1 + p2 * w2);
    qd[o] = __float2half(p0 * (w3 - w0) + p1 * (w4 - w1) + p2 * (w5 - w2) + b1l[c]);
}

// ---------------- vectorized edge accumulation on 64B half-rows ----------------
// Lane map: es = lane>>2 (16 edge slots), cg = lane&3 (4x16B col groups).
// One dwordx4 clause-load covers 16 edges. Loads issued in one clause before
// any consume (R7/R9: no per-load branches; remainder selected by wave-uniform
// branch). Masked slots load row 0 (always-hot). R12: no multi-node loops.
__device__ __forceinline__ half2v bitcast_h2(unsigned int u) {
    union { unsigned int u; half2v h; } cvt;
    cvt.u = u;
    return cvt.h;
}

__device__ __forceinline__ void edge_full64(const char* __restrict__ qsb,
                                            const ushort_t* __restrict__ colsrc,
                                            int i, int lane, int es, unsigned int cg16,
                                            const half2v qd2[4], float acc[8]) {
    const half2v z2 = {(_Float16)0.0f, (_Float16)0.0f};
    int sl = (int)__builtin_nontemporal_load(colsrc + i + lane);
    uint4 q[4];
#pragma unroll
    for (int k = 0; k < 4; ++k) {
        int s = __shfl(sl, (k << 4) + es);
        q[k] = *reinterpret_cast<const uint4*>(qsb + (((unsigned int)(s << 6)) | cg16));
    }
    half2v h[4] = {z2, z2, z2, z2};
#pragma unroll
    for (int k = 0; k < 4; ++k) {
        unsigned int wd[4] = {q[k].x, q[k].y, q[k].z, q[k].w};
#pragma unroll
        for (int d = 0; d < 4; ++d) {
            half2v r = bitcast_h2(wd[d]) + qd2[d];      // v_pk_add_f16
            r = __builtin_elementwise_max(r, z2);       // v_pk_max_f16
            h[d] += r;                                  // full chunk: no cndmask
        }
    }
#pragma unroll
    for (int d = 0; d < 4; ++d) {
        acc[2 * d]     += (float)h[d].x;
        acc[2 * d + 1] += (float)h[d].y;
    }
}

template <int NL>
__device__ __forceinline__ void edge_tail(const char* __restrict__ qsb,
                                          const ushort_t* __restrict__ colsrc,
                                          int i, int r, int lane, int es, unsigned int cg16,
                                          const half2v qd2[4], float acc[8]) {
    const half2v z2 = {(_Float16)0.0f, (_Float16)0.0f};
    int sl = (lane < r) ? (int)__builtin_nontemporal_load(colsrc + i + lane) : 0;
    uint4 q[NL];
#pragma unroll
    for (int k = 0; k < NL; ++k) {
        int s = __shfl(sl, (k << 4) + es);
        q[k] = *reinterpret_cast<const uint4*>(qsb + (((unsigned int)(s << 6)) | cg16));
    }
    half2v h[4] = {z2, z2, z2, z2};
#pragma unroll
    for (int k = 0; k < NL; ++k) {
        bool ok = ((k << 4) + es) < r;
        unsigned int wd[4] = {q[k].x, q[k].y, q[k].z, q[k].w};
#pragma unroll
        for (int d = 0; d < 4; ++d) {
            half2v t = bitcast_h2(wd[d]) + qd2[d];
            t = __builtin_elementwise_max(t, z2);
            h[d] += ok ? t : z2;
        }
    }
#pragma unroll
    for (int d = 0; d < 4; ++d) {
        acc[2 * d]     += (float)h[d].x;
        acc[2 * d + 1] += (float)h[d].y;
    }
}

// ---------------- gather: one column-half per block, hsum[64] f32 out ----------------
// Grid = 2*NGBLK; blocks [0,NGBLK) do half 0, [NGBLK,2*NGBLK) half 1 —
// dispatch-order locality heuristic only (correct under any order).
__global__ __launch_bounds__(256) void k_gatherA(
    const __half* __restrict__ qsh, const __half* __restrict__ qdh,
    const int* __restrict__ rowstart, const ushort_t* __restrict__ colsrc,
    float* __restrict__ hsum) {
    int tid = threadIdx.x;
    int w = tid >> 6, lane = tid & 63;
    int es = lane >> 2, cg = lane & 3;
    unsigned int cg16 = (unsigned int)(cg << 4);
    int bb = blockIdx.x;
    int half = (bb >= NGBLK) ? 1 : 0;
    int v = (bb - half * NGBLK) * 4 + w;
    const char* qsb = (const char*)qsh + (size_t)half * NN * 64;  // 64B per node-half
    const char* qdb = (const char*)qdh + (size_t)half * NN * 64;

    uintv4 qq = __builtin_nontemporal_load(
        reinterpret_cast<const uintv4*>(qdb + ((size_t)v << 6)) + cg);
    unsigned int qw[4] = {qq.x, qq.y, qq.z, qq.w};
    half2v qd2[4];
#pragma unroll
    for (int d = 0; d < 4; ++d) qd2[d] = bitcast_h2(qw[d]);

    float acc[8] = {0, 0, 0, 0, 0, 0, 0, 0};
    int start = rowstart[v], end = rowstart[v + 1];

    if (es == 0) {  // self loop: 4 lanes cover the 64B half-row of v
        const half2v z2 = {(_Float16)0.0f, (_Float16)0.0f};
        uint4 q = *reinterpret_cast<const uint4*>(qsb + (((unsigned int)(v << 6)) | cg16));
        unsigned int wd[4] = {q.x, q.y, q.z, q.w};
#pragma unroll
        for (int d = 0; d < 4; ++d) {
            half2v r = bitcast_h2(wd[d]) + qd2[d];
            r = __builtin_elementwise_max(r, z2);
            acc[2 * d]     += (float)r.x;
            acc[2 * d + 1] += (float)r.y;
        }
    }

    int i = start;
    while (end - i >= 64) { edge_full64(qsb, colsrc, i, lane, es, cg16, qd2, acc); i += 64; }
    int r = end - i;
    if      (r > 48) edge_tail<4>(qsb, colsrc, i, r, lane, es, cg16, qd2, acc);
    else if (r > 32) edge_tail<3>(qsb, colsrc, i, r, lane, es, cg16, qd2, acc);
    else if (r > 16) edge_tail<2>(qsb, colsrc, i, r, lane, es, cg16, qd2, acc);
    else if (r > 0)  edge_tail<1>(qsb, colsrc, i, r, lane, es, cg16, qd2, acc);

    // fold the 16 edge-slot groups (es = bits 2..5 of lane)
#pragma unroll
    for (int k = 0; k < 8; ++k) {
        acc[k] += __shfl_xor(acc[k], 4);
        acc[k] += __shfl_xor(acc[k], 8);
        acc[k] += __shfl_xor(acc[k], 16);
        acc[k] += __shfl_xor(acc[k], 32);
    }
    if (es == 0) {  // lanes 0..3 hold cols cg*8..cg*8+7 of this half
        floatv4 a0 = {acc[0], acc[1], acc[2], acc[3]};
        floatv4 a1 = {acc[4], acc[5], acc[6], acc[7]};
        floatv4* dst = reinterpret_cast<floatv4*>(hsum + (size_t)v * 64 + half * 32 + cg * 8);
        __builtin_nontemporal_store(a0, dst);
        __builtin_nontemporal_store(a1, dst + 1);
    }
}

// ---------------- projection, layers 0..4 (3 output cols) + BN partials ----------------
__global__ __launch_bounds__(256) void k_proj3(
    const float* __restrict__ hsum, const int* __restrict__ rowstart,
    const float* __restrict__ W2l, const float* __restrict__ b2l,
    float* __restrict__ pnext, float* __restrict__ gsum_l) {
    __shared__ float w2c[3][64];
    __shared__ float b2c[3];
    __shared__ float part[4][8];
    int tid = threadIdx.x;
    if (tid < 192) {
        int cj = tid >> 6;
        int col = (cj == 0) ? 0 : ((cj == 1) ? 1 : 14);
        w2c[cj][tid & 63] = W2l[(tid & 63) * 64 + col];
    }
    if (tid < 3) b2c[tid] = b2l[(tid == 0) ? 0 : ((tid == 1) ? 1 : 14)];
    __syncthreads();

    int w = tid >> 6, lane = tid & 63;
    int v = blockIdx.x * 4 + w;
    float hv = __builtin_nontemporal_load(hsum + (size_t)v * 64 + lane);
    int start = rowstart[v], end = rowstart[v + 1];
    float degp1 = (float)(end - start + 1);
#pragma unroll
    for (int j = 0; j < 3; ++j) {
        float t = hv * w2c[j][lane];
        t += __shfl_xor(t, 1);
        t += __shfl_xor(t, 2);
        t += __shfl_xor(t, 4);
        t += __shfl_xor(t, 8);
        t += __shfl_xor(t, 16);
        t += __shfl_xor(t, 32);
        if (lane == 0) {
            float val = t + degp1 * b2c[j];
            pnext[v * 3 + j] = val;
            part[w][j] = val;
            part[w][3 + j] = val * val;
        }
    }
    __syncthreads();
    if (tid < 6) {
        float ssum = part[0][tid] + part[1][tid] + part[2][tid] + part[3][tid];
        atomicAdd(&gsum_l[(blockIdx.x & (NSLOT - 1)) * 8 + tid], ssum);
    }
}

// ---------------- BN finalize: 128x8 spread slots -> scale/shift ----------------
__global__ void k_bnfin(const float* __restrict__ gs,
                        const float* __restrict__ gamma_l, const float* __restrict__ beta_l,
                        float* __restrict__ scale, float* __restrict__ shift) {
    __shared__ float red[6][8];
    __shared__ float tot[6];
    int t = threadIdx.x;            // 64 threads
    int j = t >> 3, k = t & 7;
    if (j < 6) {
        float s = 0.f;
        for (int slot = k; slot < NSLOT; slot += 8) s += gs[slot * 8 + j];
        red[j][k] = s;
    }
    __syncthreads();
    if (t < 6) {
        float s = 0.f;
#pragma unroll
        for (int k2 = 0; k2 < 8; ++k2) s += red[t][k2];
        tot[t] = s;
    }
    __syncthreads();
    if (t < 3) {
        const int cols[3] = {0, 1, 14};
        float mu = tot[t] / (float)NN;
        float var = tot[t + 3] / (float)NN - mu * mu;
        float rs = rsqrtf(var + EPSV);
        float g = gamma_l[cols[t]];
        scale[t] = rs * g;
        shift[t] = beta_l[cols[t]] - mu * rs * g;
    }
}

// ---------------- projection, layer 5: full 64-col matmul ----------------
__global__ __launch_bounds__(256) void k_projfull(
    const float* __restrict__ hsum, const int* __restrict__ rowstart,
    const float* __restrict__ W2l, const float* __restrict__ b2l,
    float* __restrict__ out) {
    __shared__ float lds[4][64];
    int tid = threadIdx.x;
    int w = tid >> 6, lane = tid & 63;
    int v = blockIdx.x * 4 + w;
    float hv = __builtin_nontemporal_load(hsum + (size_t)v * 64 + lane);
    lds[w][lane] = hv;
    __syncthreads();
    int start = rowstart[v], end = rowstart[v + 1];
    float degp1 = (float)(end - start + 1);
    float sum = degp1 * b2l[lane];
    for (int k = 0; k < 64; ++k) sum += lds[w][k] * W2l[k * 64 + lane];
    out[(size_t)v * 64 + lane] = sum;
}

// ---------------- launch ----------------

static inline size_t align_up(size_t x) { return (x + 255) & ~(size_t)255; }

extern "C" void kernel_launch(void* const* d_in, const int* in_sizes, int n_in,
                              void* d_out, int out_size, void* d_ws, size_t ws_size,
                              hipStream_t stream) {
    const float* x     = (const float*)d_in[0];
    const int*   ei    = (const int*)d_in[1];
    const float* W1    = (const float*)d_in[2];
    const float* b1    = (const float*)d_in[3];
    const float* W2    = (const float*)d_in[4];
    const float* b2    = (const float*)d_in[5];
    const float* gamma = (const float*)d_in[6];
    const float* beta  = (const float*)d_in[7];
    float* out = (float*)d_out;
    const int E = in_sizes[1] / 2;           // 1,600,000
    const int* src = ei;
    const int* dst = ei + E;

    const int nchunk = (E + CHUNK - 1) / CHUNK;     // 391
    const int nscan  = NBKT * nchunk;
    const int nsb    = (nscan + 255) / 256;

    // workspace carve
    char* base = (char*)d_ws;
    size_t off = 0;
    __half* qs = (__half*)(base + off);     off = align_up(off + (size_t)NN * 64 * 2);
    __half* qd = (__half*)(base + off);     off = align_up(off + (size_t)NN * 64 * 2);
    float* hsum = (float*)(base + off);     off = align_up(off + (size_t)NN * 64 * 4);
    float* pA = (float*)(base + off);       off = align_up(off + (size_t)NN * 3 * 4);
    float* pB = (float*)(base + off);       off = align_up(off + (size_t)NN * 3 * 4);
    int* rowstart = (int*)(base + off);     off = align_up(off + (size_t)(NN + 1) * 4);
    ushort_t* colsrc = (ushort_t*)(base + off); off = align_up(off + (size_t)E * 2);
    int* ebuf     = (int*)(base + off);     off = align_up(off + (size_t)E * 4);
    int* hist     = (int*)(base + off);     off = align_up(off + (size_t)nscan * 4);
    int* offsT    = (int*)(base + off);     off = align_up(off + (size_t)nscan * 4);
    int* presum   = (int*)(base + off);     off = align_up(off + (size_t)nscan * 4);
    int* bsum     = (int*)(base + off);     off = align_up(off + (size_t)nsb * 4);
    int* boff     = (int*)(base + off);     off = align_up(off + (size_t)nsb * 4);
    float* gsumsp = (float*)(base + off);   off = align_up(off + (size_t)5 * NSLOT * 8 * 4);
    float* scale  = (float*)(base + off);   off = align_up(off + 64 * 4);
    float* shift  = (float*)(base + off);   off = align_up(off + 64 * 4);
    (void)ws_size; (void)n_in; (void)out_size;

    // CSR build: two-stage counting sort, no hot-line atomics (also zeros gsumsp)
    k_hist1<<<nchunk, 256, 0, stream>>>(dst, E, nchunk, hist, gsumsp);
    k_scanA<<<nsb, 256, 0, stream>>>(hist, nscan, presum, bsum);
    k_scanB<<<1, 256, 0, stream>>>(bsum, nsb, boff);
    k_scanC<<<nsb, 256, 0, stream>>>(presum, hist, boff, nscan, nchunk, offsT);
    k_scatter1<<<nchunk, 256, 0, stream>>>(src, dst, E, offsT, ebuf);
    k_bucket_csr<<<NBKT, 256, 0, stream>>>(ebuf, offsT, E, rowstart, colsrc);

    float* pc = pA;
    float* pn = pB;
    for (int l = 0; l < 6; ++l) {
        const float* pin = (l == 0) ? x : pc;
        int pstride = (l == 0) ? 16 : 3;
        int c0 = 0, c1 = 1, c2 = (l == 0) ? 14 : 2;
        k_q<<<NQBLK, 256, 0, stream>>>(pin, pstride, c0, c1, c2,
                                       W1 + (size_t)l * 6 * 64, b1 + (size_t)l * 64,
                                       scale, shift, (l > 0) ? 1 : 0, qs, qd);
        k_gatherA<<<2 * NGBLK, 256, 0, stream>>>(qs, qd, rowstart, colsrc, hsum);
        if (l < 5) {
            k_proj3<<<NGBLK, 256, 0, stream>>>(hsum, rowstart,
                                               W2 + (size_t)l * 64 * 64, b2 + (size_t)l * 64,
                                               pn, gsumsp + (size_t)l * NSLOT * 8);
            k_bnfin<<<1, 64, 0, stream>>>(gsumsp + (size_t)l * NSLOT * 8,
                                          gamma + (size_t)l * 64, beta + (size_t)l * 64,
                                          scale, shift);
            float* tmp = pc; pc = pn; pn = tmp;
        } else {
            k_projfull<<<NGBLK, 256, 0, stream>>>(hsum, rowstart,
                                                  W2 + (size_t)5 * 64 * 64, b2 + (size_t)5 * 64,
                                                  out);
        }
    }
}

// Round 4
// 528.407 us; speedup vs baseline: 1.1412x; 1.1412x over previous
//
#include <hip/hip_runtime.h>
#include <hip/hip_fp16.h>
#include <cstdint>

#define NN 50000
#define NQBLK 12500             // k_q blocks: NN*64/256
#define NGBLK 12500             // gather blocks: 4 nodes/block (1 per wave)
#define EPSV 1e-5f

// bucket sort params
#define NPB 128                 // nodes per bucket
#define BSH 7                   // log2(NPB)
#define NBKT 391                // ceil(NN/NPB)
#define CHUNK 4096              // edges per stage-1 block
#define EPT 16                  // edges per thread (CHUNK/256)
#define LDSE 6144               // per-bucket LDS edge capacity

// BN partial-sum spreading: 128 slots x 8 floats per layer (64 cache lines).
// R9/R10: hot-line atomics cost ~120us; spread over 64 lines -> negligible.
#define NSLOT 128

typedef unsigned short ushort_t;
typedef _Float16 half2v __attribute__((ext_vector_type(2)));

// ---------------- stage 1: per-chunk bucket histogram (+ zero BN slots) ----------------
__global__ __launch_bounds__(256) void k_hist1(const int* __restrict__ dst, int E, int nchunk,
                                               int* __restrict__ hist, float* __restrict__ gsumsp) {
    __shared__ int cnt[NBKT];
    int t = threadIdx.x, blk = blockIdx.x;
    if (blk == 0) {
        for (int z = t; z < 5 * NSLOT * 8; z += 256) gsumsp[z] = 0.f;
    }
    for (int b = t; b < NBKT; b += 256) cnt[b] = 0;
    __syncthreads();
    int base = blk * CHUNK;
#pragma unroll
    for (int k = 0; k < EPT; ++k) {
        int e = base + k * 256 + t;
        if (e < E) atomicAdd(&cnt[dst[e] >> BSH], 1);
    }
    __syncthreads();
    for (int b = t; b < NBKT; b += 256) hist[(size_t)b * nchunk + blk] = cnt[b];
}

// ---------------- generic hierarchical exclusive scan ----------------
__global__ __launch_bounds__(256) void k_scanA(const int* __restrict__ in, int n,
                                               int* __restrict__ presum, int* __restrict__ blocksum) {
    __shared__ int lds[256];
    int t = threadIdx.x, g = blockIdx.x * 256 + t;
    int v = (g < n) ? in[g] : 0;
    lds[t] = v;
    __syncthreads();
    for (int off = 1; off < 256; off <<= 1) {
        int x = (t >= off) ? lds[t - off] : 0;
        __syncthreads();
        lds[t] += x;
        __syncthreads();
    }
    if (g < n) presum[g] = lds[t];
    if (t == 255) blocksum[blockIdx.x] = lds[255];
}

__global__ __launch_bounds__(256) void k_scanB(const int* __restrict__ blocksum,
                                               int nb, int* __restrict__ blockoff) {
    __shared__ int lds[256];
    __shared__ int carry_s;
    int t = threadIdx.x;
    if (t == 0) carry_s = 0;
    __syncthreads();
    for (int base = 0; base < nb; base += 256) {
        int g = base + t;
        int v = (g < nb) ? blocksum[g] : 0;
        lds[t] = v;
        __syncthreads();
        for (int off = 1; off < 256; off <<= 1) {
            int x = (t >= off) ? lds[t - off] : 0;
            __syncthreads();
            lds[t] += x;
            __syncthreads();
        }
        if (g < nb) blockoff[g] = lds[t] - v + carry_s;
        __syncthreads();
        if (t == 255) carry_s += lds[255];
        __syncthreads();
    }
}

__global__ __launch_bounds__(256) void k_scanC(const int* __restrict__ presum,
                                               const int* __restrict__ hist,
                                               const int* __restrict__ blockoff,
                                               int n, int nchunk, int* __restrict__ offsT) {
    int g = blockIdx.x * 256 + threadIdx.x;
    if (g < n) {
        int val = presum[g] - hist[g] + blockoff[blockIdx.x];
        int b = g / nchunk;
        int c = g - b * nchunk;
        offsT[(size_t)c * NBKT + b] = val;
    }
}

// ---------------- stage 1: partition edges into buckets ----------------
__global__ __launch_bounds__(256) void k_scatter1(const int* __restrict__ src,
                                                  const int* __restrict__ dst, int E,
                                                  const int* __restrict__ offsT,
                                                  int* __restrict__ ebuf) {
    __shared__ int pos[NBKT];
    int t = threadIdx.x, blk = blockIdx.x;
    for (int b = t; b < NBKT; b += 256) pos[b] = offsT[(size_t)blk * NBKT + b];
    __syncthreads();
    int base = blk * CHUNK;
#pragma unroll
    for (int k = 0; k < EPT; ++k) {
        int e = base + k * 256 + t;
        if (e < E) {
            int d = dst[e];
            int b = d >> BSH;
            int p = atomicAdd(&pos[b], 1);
            ebuf[p] = ((d & (NPB - 1)) << 16) | src[e];
        }
    }
}

// ---------------- stage 2: per-bucket CSR ----------------
__global__ __launch_bounds__(256) void k_bucket_csr(const int* __restrict__ ebuf,
                                                    const int* __restrict__ offsT, int E,
                                                    int* __restrict__ rowstart,
                                                    ushort_t* __restrict__ colsrc) {
    __shared__ int cnt[NPB];
    __shared__ int s[NPB];
    __shared__ int pos2[NPB];
    __shared__ ushort_t lout[LDSE];
    int t = threadIdx.x, b = blockIdx.x;
    int bstart = offsT[b];
    int bend = (b + 1 < NBKT) ? offsT[b + 1] : E;
    int m = bend - bstart;
    if (t < NPB) cnt[t] = 0;
    __syncthreads();
    for (int i = bstart + t; i < bend; i += 256) atomicAdd(&cnt[ebuf[i] >> 16], 1);
    __syncthreads();
    if (t < NPB) s[t] = cnt[t];
    __syncthreads();
    for (int off = 1; off < NPB; off <<= 1) {
        int x = (t < NPB && t >= off) ? s[t - off] : 0;
        __syncthreads();
        if (t < NPB) s[t] += x;
        __syncthreads();
    }
    if (t < NPB) {
        int excl = s[t] - cnt[t];
        int node = b * NPB + t;
        if (node < NN) rowstart[node] = bstart + excl;
        pos2[t] = excl;
    }
    __syncthreads();
    if (m <= LDSE) {
        for (int i = bstart + t; i < bend; i += 256) {
            int v = ebuf[i];
            int p = atomicAdd(&pos2[v >> 16], 1);
            lout[p] = (ushort_t)(v & 0xFFFF);
        }
        __syncthreads();
        for (int i = t; i < m; i += 256) colsrc[bstart + i] = lout[i];
    } else {
        for (int i = bstart + t; i < bend; i += 256) {
            int v = ebuf[i];
            int p = atomicAdd(&pos2[v >> 16], 1);
            colsrc[bstart + p] = (ushort_t)(v & 0xFFFF);
        }
    }
    if (b == NBKT - 1 && t == 0) rowstart[NN] = E;
}

// ---------------- per-layer: node -> ppack (16B broadcast fp16 pos) + qd fp16 ----------------
// R17: qs is rank-3 (linear in the 3 position scalars). Gathering the 128B qs
// row cost 2 random sectors/edge; instead gather a 16B packed position record
// (800KB table, L2-hot, 1 sector/edge) and reconstruct qs in-loop via pk_fma.
__global__ __launch_bounds__(256) void k_q(
    const float* __restrict__ pin, int pstride, int c0, int c1, int c2,
    const float* __restrict__ W1l, const float* __restrict__ b1l,
    const float* __restrict__ scale, const float* __restrict__ shift, int use_bn,
    uint4* __restrict__ ppack, __half* __restrict__ qd) {
    int idx = blockIdx.x * 256 + threadIdx.x;   // v*64 + c
    int v = idx >> 6, c = idx & 63;
    const float* prow = pin + (size_t)v * pstride;
    float p0 = prow[c0], p1 = prow[c1], p2 = prow[c2];
    if (use_bn) {
        p0 = fmaxf(0.f, p0 * scale[0] + shift[0]);
        p1 = fmaxf(0.f, p1 * scale[1] + shift[1]);
        p2 = fmaxf(0.f, p2 * scale[2] + shift[2]);
    }
    float w0 = W1l[0 * 64 + c], w1 = W1l[1 * 64 + c], w2 = W1l[2 * 64 + c];
    float w3 = W1l[3 * 64 + c], w4 = W1l[4 * 64 + c], w5 = W1l[5 * 64 + c];
    qd[idx] = __float2half(p0 * (w3 - w0) + p1 * (w4 - w1) + p2 * (w5 - w2) + b1l[c]);
    if (c == 0) {
        unsigned int u0 = (unsigned int)__half_as_ushort(__float2half(p0)); u0 |= u0 << 16;
        unsigned int u1 = (unsigned int)__half_as_ushort(__float2half(p1)); u1 |= u1 << 16;
        unsigned int u2 = (unsigned int)__half_as_ushort(__float2half(p2)); u2 |= u2 << 16;
        uint4 pk = {u0, u1, u2, 0u};
        ppack[v] = pk;
    }
}

// ---------------- edge accumulation: gather 16B positions, fma-reconstruct qs ----------------
// Lane map (R14): es = lane>>3 (8 edge slots), cg = lane&7 (8 feature pairs x4).
// Per clause-load: 8 distinct 16B addrs (cg lanes broadcast-coalesce). Loads
// issued in one clause before consume (R7/R9); masked slots load row 0.
__device__ __forceinline__ half2v bitcast_h2(unsigned int u) {
    union { unsigned int u; half2v h; } cvt;
    cvt.u = u;
    return cvt.h;
}

__device__ __forceinline__ void edge_math(const uint4 q, const half2v qd2[4],
                                          const half2v w0p[4], const half2v w1p[4],
                                          const half2v w2p[4], bool ok, half2v h[4]) {
    const half2v z2 = {(_Float16)0.0f, (_Float16)0.0f};
    half2v p0 = bitcast_h2(q.x), p1 = bitcast_h2(q.y), p2 = bitcast_h2(q.z);
#pragma unroll
    for (int d = 0; d < 4; ++d) {
        half2v r = p0 * w0p[d] + qd2[d];     // v_pk_fma_f16
        r = p1 * w1p[d] + r;
        r = p2 * w2p[d] + r;
        r = __builtin_elementwise_max(r, z2);
        h[d] += ok ? r : z2;
    }
}

template <int NL, bool FULL>
__device__ __forceinline__ void edge_clause(const char* __restrict__ ppb,
                                            const ushort_t* __restrict__ colsrc,
                                            int i, int r, int lane, int es,
                                            const half2v qd2[4], const half2v w0p[4],
                                            const half2v w1p[4], const half2v w2p[4],
                                            float acc[8]) {
    const half2v z2 = {(_Float16)0.0f, (_Float16)0.0f};
    int sl = (FULL || lane < r) ? (int)__builtin_nontemporal_load(colsrc + i + lane) : 0;
    uint4 q[NL];
#pragma unroll
    for (int k = 0; k < NL; ++k) {
        int s = __shfl(sl, (k << 3) + es);
        q[k] = *reinterpret_cast<const uint4*>(ppb + ((unsigned int)(s << 4)));
    }
    half2v h[4] = {z2, z2, z2, z2};
#pragma unroll
    for (int k = 0; k < NL; ++k) {
        bool ok = FULL || (((k << 3) + es) < r);
        edge_math(q[k], qd2, w0p, w1p, w2p, ok, h);
    }
#pragma unroll
    for (int d = 0; d < 4; ++d) {
        acc[2 * d]     += (float)h[d].x;
        acc[2 * d + 1] += (float)h[d].y;
    }
}

__device__ __forceinline__ void run_edges(const char* __restrict__ ppb,
                                          const ushort_t* __restrict__ colsrc,
                                          int v, int start, int end, int lane, int es,
                                          const half2v qd2[4], const half2v w0p[4],
                                          const half2v w1p[4], const half2v w2p[4],
                                          float acc[8]) {
    if (es == 0) {  // self loop: uniform 16B row of v, computed by 8 cg lanes
        const half2v z2 = {(_Float16)0.0f, (_Float16)0.0f};
        uint4 pv = *reinterpret_cast<const uint4*>(ppb + ((unsigned int)(v << 4)));
        half2v p0 = bitcast_h2(pv.x), p1 = bitcast_h2(pv.y), p2 = bitcast_h2(pv.z);
#pragma unroll
        for (int d = 0; d < 4; ++d) {
            half2v r = p0 * w0p[d] + qd2[d];
            r = p1 * w1p[d] + r;
            r = p2 * w2p[d] + r;
            r = __builtin_elementwise_max(r, z2);
            acc[2 * d]     += (float)r.x;
            acc[2 * d + 1] += (float)r.y;
        }
    }
    int i = start;
    while (end - i >= 64) {
        edge_clause<8, true>(ppb, colsrc, i, 64, lane, es, qd2, w0p, w1p, w2p, acc);
        i += 64;
    }
    int r = end - i;
    if      (r > 48) edge_clause<8, false>(ppb, colsrc, i, r, lane, es, qd2, w0p, w1p, w2p, acc);
    else if (r > 32) edge_clause<6, false>(ppb, colsrc, i, r, lane, es, qd2, w0p, w1p, w2p, acc);
    else if (r > 16) edge_clause<4, false>(ppb, colsrc, i, r, lane, es, qd2, w0p, w1p, w2p, acc);
    else if (r > 0)  edge_clause<2, false>(ppb, colsrc, i, r, lane, es, qd2, w0p, w1p, w2p, acc);
}

// build per-lane W1 half2 pairs: lane cg covers feature pairs cg*8 + 2d
__device__ __forceinline__ void load_w1(const float* __restrict__ W1l, int cg,
                                        half2v w0p[4], half2v w1p[4], half2v w2p[4]) {
#pragma unroll
    for (int d = 0; d < 4; ++d) {
        int cc = (cg << 3) + (d << 1);
        w0p[d] = half2v{(_Float16)W1l[cc],       (_Float16)W1l[cc + 1]};
        w1p[d] = half2v{(_Float16)W1l[64 + cc],  (_Float16)W1l[64 + cc + 1]};
        w2p[d] = half2v{(_Float16)W1l[128 + cc], (_Float16)W1l[128 + cc + 1]};
    }
}

// ---------------- gather + reduce, layers 0..4 (3 output cols) ----------------
__global__ __launch_bounds__(256) void k_gather3(
    const uint4* __restrict__ ppack, const __half* __restrict__ qd,
    const int* __restrict__ rowstart, const ushort_t* __restrict__ colsrc,
    const float* __restrict__ W1l, const float* __restrict__ W2l,
    const float* __restrict__ b2l,
    float* __restrict__ pnext, float* __restrict__ gsum_l) {
    __shared__ float w2c[3][64];
    __shared__ float b2c[3];
    __shared__ float part[4][8];
    int tid = threadIdx.x;
    if (tid < 192) {
        int cj = tid >> 6;
        int col = (cj == 0) ? 0 : ((cj == 1) ? 1 : 14);
        w2c[cj][tid & 63] = W2l[(tid & 63) * 64 + col];
    }
    if (tid < 3) b2c[tid] = b2l[(tid == 0) ? 0 : ((tid == 1) ? 1 : 14)];
    __syncthreads();

    int w = tid >> 6, lane = tid & 63;
    int es = lane >> 3, cg = lane & 7;
    int v = blockIdx.x * 4 + w;
    const char* ppb = (const char*)ppack;

    uint4 qq = ((const uint4*)qd)[(size_t)v * 8 + cg];
    unsigned int qw[4] = {qq.x, qq.y, qq.z, qq.w};
    half2v qd2[4];
#pragma unroll
    for (int d = 0; d < 4; ++d) qd2[d] = bitcast_h2(qw[d]);
    half2v w0p[4], w1p[4], w2p[4];
    load_w1(W1l, cg, w0p, w1p, w2p);

    float acc[8] = {0, 0, 0, 0, 0, 0, 0, 0};
    int start = rowstart[v], end = rowstart[v + 1];
    run_edges(ppb, colsrc, v, start, end, lane, es, qd2, w0p, w1p, w2p, acc);

    // project unfolded partials through the 3 W2 columns, THEN fold all 6 strides
    float degp1 = (float)(end - start + 1);
#pragma unroll
    for (int j = 0; j < 3; ++j) {
        float t = 0.f;
#pragma unroll
        for (int k = 0; k < 8; ++k) t += acc[k] * w2c[j][cg * 8 + k];
        t += __shfl_xor(t, 1);
        t += __shfl_xor(t, 2);
        t += __shfl_xor(t, 4);
        t += __shfl_xor(t, 8);
        t += __shfl_xor(t, 16);
        t += __shfl_xor(t, 32);
        if (lane == 0) {
            float val = t + degp1 * b2c[j];
            pnext[v * 3 + j] = val;
            part[w][j] = val;
            part[w][3 + j] = val * val;
        }
    }
    __syncthreads();
    if (tid < 6) {
        float ssum = part[0][tid] + part[1][tid] + part[2][tid] + part[3][tid];
        atomicAdd(&gsum_l[(blockIdx.x & (NSLOT - 1)) * 8 + tid], ssum);
    }
}

// ---------------- BN finalize: 128x8 spread slots -> scale/shift ----------------
__global__ void k_bnfin(const float* __restrict__ gs,
                        const float* __restrict__ gamma_l, const float* __restrict__ beta_l,
                        float* __restrict__ scale, float* __restrict__ shift) {
    __shared__ float red[6][8];
    __shared__ float tot[6];
    int t = threadIdx.x;            // 64 threads
    int j = t >> 3, k = t & 7;
    if (j < 6) {
        float s = 0.f;
        for (int slot = k; slot < NSLOT; slot += 8) s += gs[slot * 8 + j];
        red[j][k] = s;
    }
    __syncthreads();
    if (t < 6) {
        float s = 0.f;
#pragma unroll
        for (int k2 = 0; k2 < 8; ++k2) s += red[t][k2];
        tot[t] = s;
    }
    __syncthreads();
    if (t < 3) {
        const int cols[3] = {0, 1, 14};
        float mu = tot[t] / (float)NN;
        float var = tot[t + 3] / (float)NN - mu * mu;
        float rs = rsqrtf(var + EPSV);
        float g = gamma_l[cols[t]];
        scale[t] = rs * g;
        shift[t] = beta_l[cols[t]] - mu * rs * g;
    }
}

// ---------------- gather + full 64-col matmul, layer 5 ----------------
__global__ __launch_bounds__(256) void k_gather_full(
    const uint4* __restrict__ ppack, const __half* __restrict__ qd,
    const int* __restrict__ rowstart, const ushort_t* __restrict__ colsrc,
    const float* __restrict__ W1l, const float* __restrict__ W2l,
    const float* __restrict__ b2l,
    float* __restrict__ out) {
    __shared__ float lds[4][64];
    int tid = threadIdx.x;
    int w = tid >> 6, lane = tid & 63;
    int es = lane >> 3, cg = lane & 7;
    int v = blockIdx.x * 4 + w;
    const char* ppb = (const char*)ppack;

    uint4 qq = ((const uint4*)qd)[(size_t)v * 8 + cg];
    unsigned int qw[4] = {qq.x, qq.y, qq.z, qq.w};
    half2v qd2[4];
#pragma unroll
    for (int d = 0; d < 4; ++d) qd2[d] = bitcast_h2(qw[d]);
    half2v w0p[4], w1p[4], w2p[4];
    load_w1(W1l, cg, w0p, w1p, w2p);

    float acc[8] = {0, 0, 0, 0, 0, 0, 0, 0};
    int start = rowstart[v], end = rowstart[v + 1];
    run_edges(ppb, colsrc, v, start, end, lane, es, qd2, w0p, w1p, w2p, acc);

#pragma unroll
    for (int k = 0; k < 8; ++k) {
        acc[k] += __shfl_xor(acc[k], 8);
        acc[k] += __shfl_xor(acc[k], 16);
        acc[k] += __shfl_xor(acc[k], 32);
    }
    if (es == 0) {
#pragma unroll
        for (int k = 0; k < 8; ++k) lds[w][cg * 8 + k] = acc[k];
    }
    __syncthreads();
    float degp1 = (float)(end - start + 1);
    float sum = degp1 * b2l[lane];
    for (int k = 0; k < 64; ++k) sum += lds[w][k] * W2l[k * 64 + lane];
    out[(size_t)v * 64 + lane] = sum;
}

// ---------------- launch ----------------

static inline size_t align_up(size_t x) { return (x + 255) & ~(size_t)255; }

extern "C" void kernel_launch(void* const* d_in, const int* in_sizes, int n_in,
                              void* d_out, int out_size, void* d_ws, size_t ws_size,
                              hipStream_t stream) {
    const float* x     = (const float*)d_in[0];
    const int*   ei    = (const int*)d_in[1];
    const float* W1    = (const float*)d_in[2];
    const float* b1    = (const float*)d_in[3];
    const float* W2    = (const float*)d_in[4];
    const float* b2    = (const float*)d_in[5];
    const float* gamma = (const float*)d_in[6];
    const float* beta  = (const float*)d_in[7];
    float* out = (float*)d_out;
    const int E = in_sizes[1] / 2;           // 1,600,000
    const int* src = ei;
    const int* dst = ei + E;

    const int nchunk = (E + CHUNK - 1) / CHUNK;     // 391
    const int nscan  = NBKT * nchunk;
    const int nsb    = (nscan + 255) / 256;

    // workspace carve
    char* base = (char*)d_ws;
    size_t off = 0;
    uint4* ppack = (uint4*)(base + off);    off = align_up(off + (size_t)NN * 16);
    __half* qd = (__half*)(base + off);     off = align_up(off + (size_t)NN * 64 * 2);
    float* pA = (float*)(base + off);       off = align_up(off + (size_t)NN * 3 * 4);
    float* pB = (float*)(base + off);       off = align_up(off + (size_t)NN * 3 * 4);
    int* rowstart = (int*)(base + off);     off = align_up(off + (size_t)(NN + 1) * 4);
    ushort_t* colsrc = (ushort_t*)(base + off); off = align_up(off + (size_t)E * 2);
    int* ebuf     = (int*)(base + off);     off = align_up(off + (size_t)E * 4);
    int* hist     = (int*)(base + off);     off = align_up(off + (size_t)nscan * 4);
    int* offsT    = (int*)(base + off);     off = align_up(off + (size_t)nscan * 4);
    int* presum   = (int*)(base + off);     off = align_up(off + (size_t)nscan * 4);
    int* bsum     = (int*)(base + off);     off = align_up(off + (size_t)nsb * 4);
    int* boff     = (int*)(base + off);     off = align_up(off + (size_t)nsb * 4);
    float* gsumsp = (float*)(base + off);   off = align_up(off + (size_t)5 * NSLOT * 8 * 4);
    float* scale  = (float*)(base + off);   off = align_up(off + 64 * 4);
    float* shift  = (float*)(base + off);   off = align_up(off + 64 * 4);
    (void)ws_size; (void)n_in; (void)out_size;

    // CSR build: two-stage counting sort, no hot-line atomics (also zeros gsumsp)
    k_hist1<<<nchunk, 256, 0, stream>>>(dst, E, nchunk, hist, gsumsp);
    k_scanA<<<nsb, 256, 0, stream>>>(hist, nscan, presum, bsum);
    k_scanB<<<1, 256, 0, stream>>>(bsum, nsb, boff);
    k_scanC<<<nsb, 256, 0, stream>>>(presum, hist, boff, nscan, nchunk, offsT);
    k_scatter1<<<nchunk, 256, 0, stream>>>(src, dst, E, offsT, ebuf);
    k_bucket_csr<<<NBKT, 256, 0, stream>>>(ebuf, offsT, E, rowstart, colsrc);

    float* pc = pA;
    float* pn = pB;
    for (int l = 0; l < 6; ++l) {
        const float* pin = (l == 0) ? x : pc;
        int pstride = (l == 0) ? 16 : 3;
        int c0 = 0, c1 = 1, c2 = (l == 0) ? 14 : 2;
        const float* W1l = W1 + (size_t)l * 6 * 64;
        k_q<<<NQBLK, 256, 0, stream>>>(pin, pstride, c0, c1, c2,
                                       W1l, b1 + (size_t)l * 64,
                                       scale, shift, (l > 0) ? 1 : 0, ppack, qd);
        if (l < 5) {
            k_gather3<<<NGBLK, 256, 0, stream>>>(ppack, qd, rowstart, colsrc,
                                                 W1l, W2 + (size_t)l * 64 * 64,
                                                 b2 + (size_t)l * 64,
                                                 pn, gsumsp + (size_t)l * NSLOT * 8);
            k_bnfin<<<1, 64, 0, stream>>>(gsumsp + (size_t)l * NSLOT * 8,
                                          gamma + (size_t)l * 64, beta + (size_t)l * 64,
                                          scale, shift);
            float* tmp = pc; pc = pn; pn = tmp;
        } else {
            k_gather_full<<<NGBLK, 256, 0, stream>>>(ppack, qd, rowstart, colsrc,
                                                     W1l, W2 + (size_t)5 * 64 * 64,
                                                     b2 + (size_t)5 * 64,
                                                     out);
        }
    }
}

// Round 5
// 436.800 us; speedup vs baseline: 1.3806x; 1.2097x over previous
//
#include <hip/hip_runtime.h>
#include <hip/hip_fp16.h>
#include <cstdint>

#define NN 50000
#define NQBLK 12500             // k_q blocks: NN*64/256
#define NGBLK2 6250             // gather blocks: 8 nodes/block (2 per wave)
#define EPSV 1e-5f

// bucket sort params
#define NPB 128                 // nodes per bucket
#define BSH 7                   // log2(NPB)
#define NBKT 391                // ceil(NN/NPB)
#define CHUNK 4096              // edges per stage-1 block
#define EPT 16                  // edges per thread (CHUNK/256)
#define LDSE 6144               // per-bucket LDS edge capacity

// BN partial-sum spreading: 128 slots x 8 floats per layer (64 cache lines).
// R9/R10: hot-line atomics cost ~120us; spread over 64 lines -> negligible.
#define NSLOT 128

typedef unsigned short ushort_t;
typedef _Float16 half2v __attribute__((ext_vector_type(2)));

// ---------------- stage 1: per-chunk bucket histogram (+ zero BN slots) ----------------
__global__ __launch_bounds__(256) void k_hist1(const int* __restrict__ dst, int E, int nchunk,
                                               int* __restrict__ hist, float* __restrict__ gsumsp) {
    __shared__ int cnt[NBKT];
    int t = threadIdx.x, blk = blockIdx.x;
    if (blk == 0) {
        for (int z = t; z < 5 * NSLOT * 8; z += 256) gsumsp[z] = 0.f;
    }
    for (int b = t; b < NBKT; b += 256) cnt[b] = 0;
    __syncthreads();
    int base = blk * CHUNK;
#pragma unroll
    for (int k = 0; k < EPT; ++k) {
        int e = base + k * 256 + t;
        if (e < E) atomicAdd(&cnt[dst[e] >> BSH], 1);
    }
    __syncthreads();
    for (int b = t; b < NBKT; b += 256) hist[(size_t)b * nchunk + blk] = cnt[b];
}

// ---------------- generic hierarchical exclusive scan ----------------
__global__ __launch_bounds__(256) void k_scanA(const int* __restrict__ in, int n,
                                               int* __restrict__ presum, int* __restrict__ blocksum) {
    __shared__ int lds[256];
    int t = threadIdx.x, g = blockIdx.x * 256 + t;
    int v = (g < n) ? in[g] : 0;
    lds[t] = v;
    __syncthreads();
    for (int off = 1; off < 256; off <<= 1) {
        int x = (t >= off) ? lds[t - off] : 0;
        __syncthreads();
        lds[t] += x;
        __syncthreads();
    }
    if (g < n) presum[g] = lds[t];
    if (t == 255) blocksum[blockIdx.x] = lds[255];
}

__global__ __launch_bounds__(256) void k_scanB(const int* __restrict__ blocksum,
                                               int nb, int* __restrict__ blockoff) {
    __shared__ int lds[256];
    __shared__ int carry_s;
    int t = threadIdx.x;
    if (t == 0) carry_s = 0;
    __syncthreads();
    for (int base = 0; base < nb; base += 256) {
        int g = base + t;
        int v = (g < nb) ? blocksum[g] : 0;
        lds[t] = v;
        __syncthreads();
        for (int off = 1; off < 256; off <<= 1) {
            int x = (t >= off) ? lds[t - off] : 0;
            __syncthreads();
            lds[t] += x;
            __syncthreads();
        }
        if (g < nb) blockoff[g] = lds[t] - v + carry_s;
        __syncthreads();
        if (t == 255) carry_s += lds[255];
        __syncthreads();
    }
}

__global__ __launch_bounds__(256) void k_scanC(const int* __restrict__ presum,
                                               const int* __restrict__ hist,
                                               const int* __restrict__ blockoff,
                                               int n, int nchunk, int* __restrict__ offsT) {
    int g = blockIdx.x * 256 + threadIdx.x;
    if (g < n) {
        int val = presum[g] - hist[g] + blockoff[blockIdx.x];
        int b = g / nchunk;
        int c = g - b * nchunk;
        offsT[(size_t)c * NBKT + b] = val;
    }
}

// ---------------- stage 1: partition edges into buckets ----------------
__global__ __launch_bounds__(256) void k_scatter1(const int* __restrict__ src,
                                                  const int* __restrict__ dst, int E,
                                                  const int* __restrict__ offsT,
                                                  int* __restrict__ ebuf) {
    __shared__ int pos[NBKT];
    int t = threadIdx.x, blk = blockIdx.x;
    for (int b = t; b < NBKT; b += 256) pos[b] = offsT[(size_t)blk * NBKT + b];
    __syncthreads();
    int base = blk * CHUNK;
#pragma unroll
    for (int k = 0; k < EPT; ++k) {
        int e = base + k * 256 + t;
        if (e < E) {
            int d = dst[e];
            int b = d >> BSH;
            int p = atomicAdd(&pos[b], 1);
            ebuf[p] = ((d & (NPB - 1)) << 16) | src[e];
        }
    }
}

// ---------------- stage 2: per-bucket CSR ----------------
__global__ __launch_bounds__(256) void k_bucket_csr(const int* __restrict__ ebuf,
                                                    const int* __restrict__ offsT, int E,
                                                    int* __restrict__ rowstart,
                                                    ushort_t* __restrict__ colsrc) {
    __shared__ int cnt[NPB];
    __shared__ int s[NPB];
    __shared__ int pos2[NPB];
    __shared__ ushort_t lout[LDSE];
    int t = threadIdx.x, b = blockIdx.x;
    int bstart = offsT[b];
    int bend = (b + 1 < NBKT) ? offsT[b + 1] : E;
    int m = bend - bstart;
    if (t < NPB) cnt[t] = 0;
    __syncthreads();
    for (int i = bstart + t; i < bend; i += 256) atomicAdd(&cnt[ebuf[i] >> 16], 1);
    __syncthreads();
    if (t < NPB) s[t] = cnt[t];
    __syncthreads();
    for (int off = 1; off < NPB; off <<= 1) {
        int x = (t < NPB && t >= off) ? s[t - off] : 0;
        __syncthreads();
        if (t < NPB) s[t] += x;
        __syncthreads();
    }
    if (t < NPB) {
        int excl = s[t] - cnt[t];
        int node = b * NPB + t;
        if (node < NN) rowstart[node] = bstart + excl;
        pos2[t] = excl;
    }
    __syncthreads();
    if (m <= LDSE) {
        for (int i = bstart + t; i < bend; i += 256) {
            int v = ebuf[i];
            int p = atomicAdd(&pos2[v >> 16], 1);
            lout[p] = (ushort_t)(v & 0xFFFF);
        }
        __syncthreads();
        for (int i = t; i < m; i += 256) colsrc[bstart + i] = lout[i];
    } else {
        for (int i = bstart + t; i < bend; i += 256) {
            int v = ebuf[i];
            int p = atomicAdd(&pos2[v >> 16], 1);
            colsrc[bstart + p] = (ushort_t)(v & 0xFFFF);
        }
    }
    if (b == NBKT - 1 && t == 0) rowstart[NN] = E;
}

// ---------------- per-layer: node -> (q_s, q_d) in fp16 (R14 form) ----------------
__global__ __launch_bounds__(256) void k_q(
    const float* __restrict__ pin, int pstride, int c0, int c1, int c2,
    const float* __restrict__ W1l, const float* __restrict__ b1l,
    const float* __restrict__ scale, const float* __restrict__ shift, int use_bn,
    __half* __restrict__ qs, __half* __restrict__ qd) {
    int idx = blockIdx.x * 256 + threadIdx.x;   // v*64 + c
    int v = idx >> 6, c = idx & 63;
    const float* prow = pin + (size_t)v * pstride;
    float p0 = prow[c0], p1 = prow[c1], p2 = prow[c2];
    if (use_bn) {
        p0 = fmaxf(0.f, p0 * scale[0] + shift[0]);
        p1 = fmaxf(0.f, p1 * scale[1] + shift[1]);
        p2 = fmaxf(0.f, p2 * scale[2] + shift[2]);
    }
    float w0 = W1l[0 * 64 + c], w1 = W1l[1 * 64 + c], w2 = W1l[2 * 64 + c];
    float w3 = W1l[3 * 64 + c], w4 = W1l[4 * 64 + c], w5 = W1l[5 * 64 + c];
    qs[idx] = __float2half(p0 * w0 + p1 * w1 + p2 * w2);
    qd[idx] = __float2half(p0 * (w3 - w0) + p1 * (w4 - w1) + p2 * (w5 - w2) + b1l[c]);
}

// ---------------- edge accumulation helpers (R7/R14 form) ----------------
// R9: no per-load branches; masked slots load row 0. R13: no device fences.
// R18: two nodes per wave — paired 4-load clauses (A then B, 8 loads in
// flight) amortize the fixed per-wave latency chain over 2 nodes.
__device__ __forceinline__ half2v bitcast_h2(unsigned int u) {
    union { unsigned int u; half2v h; } cvt;
    cvt.u = u;
    return cvt.h;
}

__device__ __forceinline__ void accum8f(const char* __restrict__ qsb, unsigned int byteoff,
                                        const half2v qd2[4], float acc[8]) {
    uint4 q = *reinterpret_cast<const uint4*>(qsb + byteoff);
    unsigned int wd[4] = {q.x, q.y, q.z, q.w};
    const half2v z2 = {(_Float16)0.0f, (_Float16)0.0f};
#pragma unroll
    for (int d = 0; d < 4; ++d) {
        half2v r = bitcast_h2(wd[d]) + qd2[d];
        r = __builtin_elementwise_max(r, z2);
        acc[2 * d]     += (float)r.x;
        acc[2 * d + 1] += (float)r.y;
    }
}

__device__ __forceinline__ void chunk_math32(const uint4 q[4], const half2v qd2[4],
                                             int r, int es, float acc[8]) {
    const half2v z2 = {(_Float16)0.0f, (_Float16)0.0f};
    half2v h[4] = {z2, z2, z2, z2};
#pragma unroll
    for (int k = 0; k < 4; ++k) {
        bool ok = ((k << 3) + es) < r;
        unsigned int wd[4] = {q[k].x, q[k].y, q[k].z, q[k].w};
#pragma unroll
        for (int d = 0; d < 4; ++d) {
            half2v t = bitcast_h2(wd[d]) + qd2[d];      // v_pk_add_f16
            t = __builtin_elementwise_max(t, z2);       // v_pk_max_f16
            h[d] += ok ? t : z2;                        // cndmask + pk_add
        }
    }
#pragma unroll
    for (int d = 0; d < 4; ++d) {
        acc[2 * d]     += (float)h[d].x;
        acc[2 * d + 1] += (float)h[d].y;
    }
}

// paired loop: nodes A [iA,e0) and B [iB,e1); 32-slot masked clause per node
// per iteration, A-loads and B-loads issued back-to-back before any math.
__device__ __forceinline__ void pair_edge_loop(const char* __restrict__ qsb,
                                               const ushort_t* __restrict__ colsrc,
                                               int iA, int e0, int iB, int e1,
                                               int lane, int es, unsigned int cg16,
                                               const half2v qd2A[4], const half2v qd2B[4],
                                               float accA[8], float accB[8]) {
    while (iA < e0 || iB < e1) {
        int remA = e0 - iA, remB = e1 - iB;
        int rA = remA > 32 ? 32 : remA;
        int rB = remB > 32 ? 32 : remB;
        int slA = (lane < rA) ? (int)colsrc[iA + lane] : 0;
        int slB = (lane < rB) ? (int)colsrc[iB + lane] : 0;
        uint4 qA[4], qB[4];
#pragma unroll
        for (int k = 0; k < 4; ++k) {
            int s = __shfl(slA, (k << 3) + es);
            qA[k] = *reinterpret_cast<const uint4*>(qsb + (((unsigned int)(s << 7)) | cg16));
        }
#pragma unroll
        for (int k = 0; k < 4; ++k) {
            int s = __shfl(slB, (k << 3) + es);
            qB[k] = *reinterpret_cast<const uint4*>(qsb + (((unsigned int)(s << 7)) | cg16));
        }
        chunk_math32(qA, qd2A, rA, es, accA);
        chunk_math32(qB, qd2B, rB, es, accB);
        iA += rA;
        iB += rB;
    }
}

// ---------------- gather + reduce, layers 0..4 (3 output cols), 2 nodes/wave ----------------
__global__ __launch_bounds__(256, 4) void k_gather3(
    const __half* __restrict__ qs, const __half* __restrict__ qd,
    const int* __restrict__ rowstart, const ushort_t* __restrict__ colsrc,
    const float* __restrict__ W2l, const float* __restrict__ b2l,
    float* __restrict__ pnext, float* __restrict__ gsum_l) {
    __shared__ float w2c[3][64];
    __shared__ float b2c[3];
    __shared__ float part[4][8];
    int tid = threadIdx.x;
    if (tid < 192) {
        int cj = tid >> 6;
        int col = (cj == 0) ? 0 : ((cj == 1) ? 1 : 14);
        w2c[cj][tid & 63] = W2l[(tid & 63) * 64 + col];
    }
    if (tid < 3) b2c[tid] = b2l[(tid == 0) ? 0 : ((tid == 1) ? 1 : 14)];
    __syncthreads();

    int w = tid >> 6, lane = tid & 63;
    int es = lane >> 3, cg = lane & 7;
    unsigned int cg16 = (unsigned int)(cg << 4);
    int v0 = (blockIdx.x * 4 + w) * 2;          // nodes v0, v0+1
    const char* qsb = (const char*)qs;

    uint4 qqA = ((const uint4*)qd)[(size_t)v0 * 8 + cg];
    uint4 qqB = ((const uint4*)qd)[(size_t)(v0 + 1) * 8 + cg];
    half2v qd2A[4], qd2B[4];
    {
        unsigned int qa[4] = {qqA.x, qqA.y, qqA.z, qqA.w};
        unsigned int qb[4] = {qqB.x, qqB.y, qqB.z, qqB.w};
#pragma unroll
        for (int d = 0; d < 4; ++d) { qd2A[d] = bitcast_h2(qa[d]); qd2B[d] = bitcast_h2(qb[d]); }
    }

    float accA[8] = {0, 0, 0, 0, 0, 0, 0, 0};
    float accB[8] = {0, 0, 0, 0, 0, 0, 0, 0};
    int s0 = rowstart[v0], e0 = rowstart[v0 + 1], e1 = rowstart[v0 + 2];
    if (es == 0) {  // self loops
        accum8f(qsb, ((unsigned int)(v0 << 7)) | cg16, qd2A, accA);
        accum8f(qsb, ((unsigned int)((v0 + 1) << 7)) | cg16, qd2B, accB);
    }
    pair_edge_loop(qsb, colsrc, s0, e0, e0, e1, lane, es, cg16, qd2A, qd2B, accA, accB);

    // project unfolded partials through the 3 W2 columns, fold all 6 strides
    float degA = (float)(e0 - s0 + 1);
    float degB = (float)(e1 - e0 + 1);
#pragma unroll
    for (int j = 0; j < 3; ++j) {
        float tA = 0.f, tB = 0.f;
#pragma unroll
        for (int k = 0; k < 8; ++k) {
            float wv = w2c[j][cg * 8 + k];
            tA += accA[k] * wv;
            tB += accB[k] * wv;
        }
        tA += __shfl_xor(tA, 1);  tB += __shfl_xor(tB, 1);
        tA += __shfl_xor(tA, 2);  tB += __shfl_xor(tB, 2);
        tA += __shfl_xor(tA, 4);  tB += __shfl_xor(tB, 4);
        tA += __shfl_xor(tA, 8);  tB += __shfl_xor(tB, 8);
        tA += __shfl_xor(tA, 16); tB += __shfl_xor(tB, 16);
        tA += __shfl_xor(tA, 32); tB += __shfl_xor(tB, 32);
        if (lane == 0) {
            float valA = tA + degA * b2c[j];
            float valB = tB + degB * b2c[j];
            pnext[v0 * 3 + j] = valA;
            pnext[(v0 + 1) * 3 + j] = valB;
            part[w][j] = valA + valB;
            part[w][3 + j] = valA * valA + valB * valB;
        }
    }
    __syncthreads();
    if (tid < 6) {
        float ssum = part[0][tid] + part[1][tid] + part[2][tid] + part[3][tid];
        atomicAdd(&gsum_l[(blockIdx.x & (NSLOT - 1)) * 8 + tid], ssum);
    }
}

// ---------------- BN finalize: 128x8 spread slots -> scale/shift ----------------
__global__ void k_bnfin(const float* __restrict__ gs,
                        const float* __restrict__ gamma_l, const float* __restrict__ beta_l,
                        float* __restrict__ scale, float* __restrict__ shift) {
    __shared__ float red[6][8];
    __shared__ float tot[6];
    int t = threadIdx.x;            // 64 threads
    int j = t >> 3, k = t & 7;
    if (j < 6) {
        float s = 0.f;
        for (int slot = k; slot < NSLOT; slot += 8) s += gs[slot * 8 + j];
        red[j][k] = s;
    }
    __syncthreads();
    if (t < 6) {
        float s = 0.f;
#pragma unroll
        for (int k2 = 0; k2 < 8; ++k2) s += red[t][k2];
        tot[t] = s;
    }
    __syncthreads();
    if (t < 3) {
        const int cols[3] = {0, 1, 14};
        float mu = tot[t] / (float)NN;
        float var = tot[t + 3] / (float)NN - mu * mu;
        float rs = rsqrtf(var + EPSV);
        float g = gamma_l[cols[t]];
        scale[t] = rs * g;
        shift[t] = beta_l[cols[t]] - mu * rs * g;
    }
}

// ---------------- gather + full 64-col matmul, layer 5, 2 nodes/wave ----------------
__global__ __launch_bounds__(256, 4) void k_gather_full(
    const __half* __restrict__ qs, const __half* __restrict__ qd,
    const int* __restrict__ rowstart, const ushort_t* __restrict__ colsrc,
    const float* __restrict__ W2l, const float* __restrict__ b2l,
    float* __restrict__ out) {
    __shared__ float lds[4][2][64];
    int tid = threadIdx.x;
    int w = tid >> 6, lane = tid & 63;
    int es = lane >> 3, cg = lane & 7;
    unsigned int cg16 = (unsigned int)(cg << 4);
    int v0 = (blockIdx.x * 4 + w) * 2;
    const char* qsb = (const char*)qs;

    uint4 qqA = ((const uint4*)qd)[(size_t)v0 * 8 + cg];
    uint4 qqB = ((const uint4*)qd)[(size_t)(v0 + 1) * 8 + cg];
    half2v qd2A[4], qd2B[4];
    {
        unsigned int qa[4] = {qqA.x, qqA.y, qqA.z, qqA.w};
        unsigned int qb[4] = {qqB.x, qqB.y, qqB.z, qqB.w};
#pragma unroll
        for (int d = 0; d < 4; ++d) { qd2A[d] = bitcast_h2(qa[d]); qd2B[d] = bitcast_h2(qb[d]); }
    }

    float accA[8] = {0, 0, 0, 0, 0, 0, 0, 0};
    float accB[8] = {0, 0, 0, 0, 0, 0, 0, 0};
    int s0 = rowstart[v0], e0 = rowstart[v0 + 1], e1 = rowstart[v0 + 2];
    if (es == 0) {
        accum8f(qsb, ((unsigned int)(v0 << 7)) | cg16, qd2A, accA);
        accum8f(qsb, ((unsigned int)((v0 + 1) << 7)) | cg16, qd2B, accB);
    }
    pair_edge_loop(qsb, colsrc, s0, e0, e0, e1, lane, es, cg16, qd2A, qd2B, accA, accB);

#pragma unroll
    for (int k = 0; k < 8; ++k) {
        accA[k] += __shfl_xor(accA[k], 8);
        accA[k] += __shfl_xor(accA[k], 16);
        accA[k] += __shfl_xor(accA[k], 32);
        accB[k] += __shfl_xor(accB[k], 8);
        accB[k] += __shfl_xor(accB[k], 16);
        accB[k] += __shfl_xor(accB[k], 32);
    }
    if (es == 0) {
#pragma unroll
        for (int k = 0; k < 8; ++k) {
            lds[w][0][cg * 8 + k] = accA[k];
            lds[w][1][cg * 8 + k] = accB[k];
        }
    }
    __syncthreads();
    float degA = (float)(e0 - s0 + 1);
    float degB = (float)(e1 - e0 + 1);
    float bl = b2l[lane];
    float sumA = degA * bl;
    float sumB = degB * bl;
    for (int k = 0; k < 64; ++k) {
        float wv = W2l[k * 64 + lane];
        sumA += lds[w][0][k] * wv;
        sumB += lds[w][1][k] * wv;
    }
    out[(size_t)v0 * 64 + lane] = sumA;
    out[(size_t)(v0 + 1) * 64 + lane] = sumB;
}

// ---------------- launch ----------------

static inline size_t align_up(size_t x) { return (x + 255) & ~(size_t)255; }

extern "C" void kernel_launch(void* const* d_in, const int* in_sizes, int n_in,
                              void* d_out, int out_size, void* d_ws, size_t ws_size,
                              hipStream_t stream) {
    const float* x     = (const float*)d_in[0];
    const int*   ei    = (const int*)d_in[1];
    const float* W1    = (const float*)d_in[2];
    const float* b1    = (const float*)d_in[3];
    const float* W2    = (const float*)d_in[4];
    const float* b2    = (const float*)d_in[5];
    const float* gamma = (const float*)d_in[6];
    const float* beta  = (const float*)d_in[7];
    float* out = (float*)d_out;
    const int E = in_sizes[1] / 2;           // 1,600,000
    const int* src = ei;
    const int* dst = ei + E;

    const int nchunk = (E + CHUNK - 1) / CHUNK;     // 391
    const int nscan  = NBKT * nchunk;
    const int nsb    = (nscan + 255) / 256;

    // workspace carve
    char* base = (char*)d_ws;
    size_t off = 0;
    __half* qs = (__half*)(base + off);     off = align_up(off + (size_t)NN * 64 * 2);
    __half* qd = (__half*)(base + off);     off = align_up(off + (size_t)NN * 64 * 2);
    float* pA = (float*)(base + off);       off = align_up(off + (size_t)NN * 3 * 4);
    float* pB = (float*)(base + off);       off = align_up(off + (size_t)NN * 3 * 4);
    int* rowstart = (int*)(base + off);     off = align_up(off + (size_t)(NN + 1) * 4);
    ushort_t* colsrc = (ushort_t*)(base + off); off = align_up(off + (size_t)E * 2);
    int* ebuf     = (int*)(base + off);     off = align_up(off + (size_t)E * 4);
    int* hist     = (int*)(base + off);     off = align_up(off + (size_t)nscan * 4);
    int* offsT    = (int*)(base + off);     off = align_up(off + (size_t)nscan * 4);
    int* presum   = (int*)(base + off);     off = align_up(off + (size_t)nscan * 4);
    int* bsum     = (int*)(base + off);     off = align_up(off + (size_t)nsb * 4);
    int* boff     = (int*)(base + off);     off = align_up(off + (size_t)nsb * 4);
    float* gsumsp = (float*)(base + off);   off = align_up(off + (size_t)5 * NSLOT * 8 * 4);
    float* scale  = (float*)(base + off);   off = align_up(off + 64 * 4);
    float* shift  = (float*)(base + off);   off = align_up(off + 64 * 4);
    (void)ws_size; (void)n_in; (void)out_size;

    // CSR build: two-stage counting sort, no hot-line atomics (also zeros gsumsp)
    k_hist1<<<nchunk, 256, 0, stream>>>(dst, E, nchunk, hist, gsumsp);
    k_scanA<<<nsb, 256, 0, stream>>>(hist, nscan, presum, bsum);
    k_scanB<<<1, 256, 0, stream>>>(bsum, nsb, boff);
    k_scanC<<<nsb, 256, 0, stream>>>(presum, hist, boff, nscan, nchunk, offsT);
    k_scatter1<<<nchunk, 256, 0, stream>>>(src, dst, E, offsT, ebuf);
    k_bucket_csr<<<NBKT, 256, 0, stream>>>(ebuf, offsT, E, rowstart, colsrc);

    float* pc = pA;
    float* pn = pB;
    for (int l = 0; l < 6; ++l) {
        const float* pin = (l == 0) ? x : pc;
        int pstride = (l == 0) ? 16 : 3;
        int c0 = 0, c1 = 1, c2 = (l == 0) ? 14 : 2;
        k_q<<<NQBLK, 256, 0, stream>>>(pin, pstride, c0, c1, c2,
                                       W1 + (size_t)l * 6 * 64, b1 + (size_t)l * 64,
                                       scale, shift, (l > 0) ? 1 : 0, qs, qd);
        if (l < 5) {
            k_gather3<<<NGBLK2, 256, 0, stream>>>(qs, qd, rowstart, colsrc,
                                                  W2 + (size_t)l * 64 * 64, b2 + (size_t)l * 64,
                                                  pn, gsumsp + (size_t)l * NSLOT * 8);
            k_bnfin<<<1, 64, 0, stream>>>(gsumsp + (size_t)l * NSLOT * 8,
                                          gamma + (size_t)l * 64, beta + (size_t)l * 64,
                                          scale, shift);
            float* tmp = pc; pc = pn; pn = tmp;
        } else {
            k_gather_full<<<NGBLK2, 256, 0, stream>>>(qs, qd, rowstart, colsrc,
                                                      W2 + (size_t)5 * 64 * 64, b2 + (size_t)5 * 64,
                                                      out);
        }
    }
}

// Round 6
// 404.579 us; speedup vs baseline: 1.4905x; 1.0796x over previous
//
#include <hip/hip_runtime.h>
#include <hip/hip_fp16.h>
#include <cstdint>

#define NN 50000
#define NQBLK8 1563             // k_q blocks: NN*8/256 rounded up
#define NGBLK2 6250             // gather blocks: 8 nodes/block (2 per wave)
#define EPSV 1e-5f

// bucket sort params
#define NPB 128                 // nodes per bucket
#define BSH 7                   // log2(NPB)
#define NBKT 391                // ceil(NN/NPB)
#define CHUNK 4096              // edges per stage-1 block
#define EPT 16                  // edges per thread (CHUNK/256)
#define LDSE 6144               // per-bucket LDS edge capacity

// BN partial-sum spreading: 128 slots x 8 floats per layer (64 cache lines).
// R9/R10: hot-line atomics cost ~120us; spread over 64 lines -> negligible.
#define NSLOT 128

typedef unsigned short ushort_t;
typedef _Float16 half2v __attribute__((ext_vector_type(2)));

// ---------------- stage 1: per-chunk bucket histogram (+ zero BN slots) ----------------
__global__ __launch_bounds__(256) void k_hist1(const int* __restrict__ dst, int E, int nchunk,
                                               int* __restrict__ hist, float* __restrict__ gsumsp) {
    __shared__ int cnt[NBKT];
    int t = threadIdx.x, blk = blockIdx.x;
    if (blk == 0) {
        for (int z = t; z < 5 * NSLOT * 8; z += 256) gsumsp[z] = 0.f;
    }
    for (int b = t; b < NBKT; b += 256) cnt[b] = 0;
    __syncthreads();
    int base = blk * CHUNK;
#pragma unroll
    for (int k = 0; k < EPT; ++k) {
        int e = base + k * 256 + t;
        if (e < E) atomicAdd(&cnt[dst[e] >> BSH], 1);
    }
    __syncthreads();
    for (int b = t; b < NBKT; b += 256) hist[(size_t)b * nchunk + blk] = cnt[b];
}

// ---------------- hierarchical exclusive scan (A: per-block, C: fused apply) ----------------
__global__ __launch_bounds__(256) void k_scanA(const int* __restrict__ in, int n,
                                               int* __restrict__ presum, int* __restrict__ blocksum) {
    __shared__ int lds[256];
    int t = threadIdx.x, g = blockIdx.x * 256 + t;
    int v = (g < n) ? in[g] : 0;
    lds[t] = v;
    __syncthreads();
    for (int off = 1; off < 256; off <<= 1) {
        int x = (t >= off) ? lds[t - off] : 0;
        __syncthreads();
        lds[t] += x;
        __syncthreads();
    }
    if (g < n) presum[g] = lds[t];
    if (t == 255) blocksum[blockIdx.x] = lds[255];
}

// fused scanB+scanC: each block computes its own carry (sum of blocksum[0..blk))
__global__ __launch_bounds__(256) void k_scanC(const int* __restrict__ presum,
                                               const int* __restrict__ hist,
                                               const int* __restrict__ blocksum,
                                               int n, int nchunk, int* __restrict__ offsT) {
    __shared__ int lds[256];
    int t = threadIdx.x, myblk = blockIdx.x;
    int acc = 0;
    for (int i = t; i < myblk; i += 256) acc += blocksum[i];
    lds[t] = acc;
    __syncthreads();
    for (int off = 128; off > 0; off >>= 1) {
        if (t < off) lds[t] += lds[t + off];
        __syncthreads();
    }
    int boff = lds[0];
    int g = myblk * 256 + t;
    if (g < n) {
        int val = presum[g] - hist[g] + boff;
        int b = g / nchunk;
        int c = g - b * nchunk;
        offsT[(size_t)c * NBKT + b] = val;
    }
}

// ---------------- stage 1: partition edges into buckets ----------------
__global__ __launch_bounds__(256) void k_scatter1(const int* __restrict__ src,
                                                  const int* __restrict__ dst, int E,
                                                  const int* __restrict__ offsT,
                                                  int* __restrict__ ebuf) {
    __shared__ int pos[NBKT];
    int t = threadIdx.x, blk = blockIdx.x;
    for (int b = t; b < NBKT; b += 256) pos[b] = offsT[(size_t)blk * NBKT + b];
    __syncthreads();
    int base = blk * CHUNK;
#pragma unroll
    for (int k = 0; k < EPT; ++k) {
        int e = base + k * 256 + t;
        if (e < E) {
            int d = dst[e];
            int b = d >> BSH;
            int p = atomicAdd(&pos[b], 1);
            ebuf[p] = ((d & (NPB - 1)) << 16) | src[e];
        }
    }
}

// ---------------- stage 2: per-bucket CSR ----------------
__global__ __launch_bounds__(256) void k_bucket_csr(const int* __restrict__ ebuf,
                                                    const int* __restrict__ offsT, int E,
                                                    int* __restrict__ rowstart,
                                                    ushort_t* __restrict__ colsrc) {
    __shared__ int cnt[NPB];
    __shared__ int s[NPB];
    __shared__ int pos2[NPB];
    __shared__ ushort_t lout[LDSE];
    int t = threadIdx.x, b = blockIdx.x;
    int bstart = offsT[b];
    int bend = (b + 1 < NBKT) ? offsT[b + 1] : E;
    int m = bend - bstart;
    if (t < NPB) cnt[t] = 0;
    __syncthreads();
    for (int i = bstart + t; i < bend; i += 256) atomicAdd(&cnt[ebuf[i] >> 16], 1);
    __syncthreads();
    if (t < NPB) s[t] = cnt[t];
    __syncthreads();
    for (int off = 1; off < NPB; off <<= 1) {
        int x = (t < NPB && t >= off) ? s[t - off] : 0;
        __syncthreads();
        if (t < NPB) s[t] += x;
        __syncthreads();
    }
    if (t < NPB) {
        int excl = s[t] - cnt[t];
        int node = b * NPB + t;
        if (node < NN) rowstart[node] = bstart + excl;
        pos2[t] = excl;
    }
    __syncthreads();
    if (m <= LDSE) {
        for (int i = bstart + t; i < bend; i += 256) {
            int v = ebuf[i];
            int p = atomicAdd(&pos2[v >> 16], 1);
            lout[p] = (ushort_t)(v & 0xFFFF);
        }
        __syncthreads();
        for (int i = t; i < m; i += 256) colsrc[bstart + i] = lout[i];
    } else {
        for (int i = bstart + t; i < bend; i += 256) {
            int v = ebuf[i];
            int p = atomicAdd(&pos2[v >> 16], 1);
            colsrc[bstart + p] = (ushort_t)(v & 0xFFFF);
        }
    }
    if (b == NBKT - 1 && t == 0) rowstart[NN] = E;
}

// ---------------- per-layer: node -> (q_s, q_d), BN-finalize fused in-block ----------------
// R19: 8 features/thread, one 16B store per table per thread (was 2B stores).
// BN finalize (was k_bnfin) now computed redundantly per block from the 4KB
// L2-hot gsum slab — removes 5 single-block dispatches from the critical path.
__global__ __launch_bounds__(256) void k_q(
    const float* __restrict__ pin, int pstride, int c0, int c1, int c2,
    const float* __restrict__ W1l, const float* __restrict__ b1l,
    const float* __restrict__ gsum_prev, const float* __restrict__ gamma_l,
    const float* __restrict__ beta_l, int use_bn,
    __half* __restrict__ qs, __half* __restrict__ qd) {
    __shared__ float red[6][8];
    __shared__ float scv[3], shv[3];
    int tid = threadIdx.x;
    if (use_bn) {
        if (tid < 48) {
            int j = tid >> 3, k = tid & 7;
            float s = 0.f;
            for (int slot = k; slot < NSLOT; slot += 8) s += gsum_prev[slot * 8 + j];
            red[j][k] = s;
        }
        __syncthreads();
        if (tid < 3) {
            const int cols[3] = {0, 1, 14};
            float sum = 0.f, sumsq = 0.f;
#pragma unroll
            for (int k2 = 0; k2 < 8; ++k2) { sum += red[tid][k2]; sumsq += red[tid + 3][k2]; }
            float mu = sum / (float)NN;
            float var = sumsq / (float)NN - mu * mu;
            float rs = rsqrtf(var + EPSV);
            float g = gamma_l[cols[tid]];
            scv[tid] = rs * g;
            shv[tid] = beta_l[cols[tid]] - mu * rs * g;
        }
        __syncthreads();
    }
    int idx = blockIdx.x * 256 + tid;
    int v = idx >> 3, g = idx & 7;
    if (v >= NN) return;
    const float* prow = pin + (size_t)v * pstride;
    float p0 = prow[c0], p1 = prow[c1], p2 = prow[c2];
    if (use_bn) {
        p0 = fmaxf(0.f, p0 * scv[0] + shv[0]);
        p1 = fmaxf(0.f, p1 * scv[1] + shv[1]);
        p2 = fmaxf(0.f, p2 * scv[2] + shv[2]);
    }
    unsigned int us[4], ud[4];
#pragma unroll
    for (int pr = 0; pr < 4; ++pr) {
        int c = (g << 3) + (pr << 1);
        float w0a = W1l[c], w1a = W1l[64 + c], w2a = W1l[128 + c];
        float qsa = p0 * w0a + p1 * w1a + p2 * w2a;
        float qda = p0 * (W1l[192 + c] - w0a) + p1 * (W1l[256 + c] - w1a)
                  + p2 * (W1l[320 + c] - w2a) + b1l[c];
        int c1i = c + 1;
        float w0b = W1l[c1i], w1b = W1l[64 + c1i], w2b = W1l[128 + c1i];
        float qsb = p0 * w0b + p1 * w1b + p2 * w2b;
        float qdb = p0 * (W1l[192 + c1i] - w0b) + p1 * (W1l[256 + c1i] - w1b)
                  + p2 * (W1l[320 + c1i] - w2b) + b1l[c1i];
        us[pr] = (unsigned int)__half_as_ushort(__float2half(qsa))
               | ((unsigned int)__half_as_ushort(__float2half(qsb)) << 16);
        ud[pr] = (unsigned int)__half_as_ushort(__float2half(qda))
               | ((unsigned int)__half_as_ushort(__float2half(qdb)) << 16);
    }
    uint4 vs = {us[0], us[1], us[2], us[3]};
    uint4 vd = {ud[0], ud[1], ud[2], ud[3]};
    ((uint4*)qs)[(size_t)v * 8 + g] = vs;
    ((uint4*)qd)[(size_t)v * 8 + g] = vd;
}

// ---------------- edge accumulation helpers ----------------
// R9: no per-load branches; masked slots load row 0. R13: no device fences.
// R18: two nodes per wave (paired clauses, 8 loads in flight).
// R19: colsrc for iteration i+1 prefetched before the math of iteration i —
// hides the ~300cy colsrc fetch under pk-math, shortening the per-wave chain.
__device__ __forceinline__ half2v bitcast_h2(unsigned int u) {
    union { unsigned int u; half2v h; } cvt;
    cvt.u = u;
    return cvt.h;
}

__device__ __forceinline__ void accum8f(const char* __restrict__ qsb, unsigned int byteoff,
                                        const half2v qd2[4], float acc[8]) {
    uint4 q = *reinterpret_cast<const uint4*>(qsb + byteoff);
    unsigned int wd[4] = {q.x, q.y, q.z, q.w};
    const half2v z2 = {(_Float16)0.0f, (_Float16)0.0f};
#pragma unroll
    for (int d = 0; d < 4; ++d) {
        half2v r = bitcast_h2(wd[d]) + qd2[d];
        r = __builtin_elementwise_max(r, z2);
        acc[2 * d]     += (float)r.x;
        acc[2 * d + 1] += (float)r.y;
    }
}

__device__ __forceinline__ void chunk_math32(const uint4 q[4], const half2v qd2[4],
                                             int r, int es, float acc[8]) {
    const half2v z2 = {(_Float16)0.0f, (_Float16)0.0f};
    half2v h[4] = {z2, z2, z2, z2};
#pragma unroll
    for (int k = 0; k < 4; ++k) {
        bool ok = ((k << 3) + es) < r;
        unsigned int wd[4] = {q[k].x, q[k].y, q[k].z, q[k].w};
#pragma unroll
        for (int d = 0; d < 4; ++d) {
            half2v t = bitcast_h2(wd[d]) + qd2[d];      // v_pk_add_f16
            t = __builtin_elementwise_max(t, z2);       // v_pk_max_f16
            h[d] += ok ? t : z2;                        // cndmask + pk_add
        }
    }
#pragma unroll
    for (int d = 0; d < 4; ++d) {
        acc[2 * d]     += (float)h[d].x;
        acc[2 * d + 1] += (float)h[d].y;
    }
}

__device__ __forceinline__ int clamp32(int x) { return x < 32 ? (x < 0 ? 0 : x) : 32; }

// paired + pipelined loop: nodes A [iA,e0) and B [iB,e1)
__device__ __forceinline__ void pair_edge_loop(const char* __restrict__ qsb,
                                               const ushort_t* __restrict__ colsrc,
                                               int iA, int e0, int iB, int e1,
                                               int lane, int es, unsigned int cg16,
                                               const half2v qd2A[4], const half2v qd2B[4],
                                               float accA[8], float accB[8]) {
    int rA = clamp32(e0 - iA);
    int rB = clamp32(e1 - iB);
    if (rA == 0 && rB == 0) return;
    int slA = (lane < rA) ? (int)colsrc[iA + lane] : 0;
    int slB = (lane < rB) ? (int)colsrc[iB + lane] : 0;
    while (true) {
        uint4 qA[4], qB[4];
#pragma unroll
        for (int k = 0; k < 4; ++k) {
            int s = __shfl(slA, (k << 3) + es);
            qA[k] = *reinterpret_cast<const uint4*>(qsb + (((unsigned int)(s << 7)) | cg16));
        }
#pragma unroll
        for (int k = 0; k < 4; ++k) {
            int s = __shfl(slB, (k << 3) + es);
            qB[k] = *reinterpret_cast<const uint4*>(qsb + (((unsigned int)(s << 7)) | cg16));
        }
        int iA2 = iA + rA, iB2 = iB + rB;
        int rA2 = clamp32(e0 - iA2);
        int rB2 = clamp32(e1 - iB2);
        bool more = (rA2 > 0) || (rB2 > 0);
        int slA2 = 0, slB2 = 0;
        if (more) {     // wave-uniform; prefetch next colsrc words before math
            slA2 = (lane < rA2) ? (int)colsrc[iA2 + lane] : 0;
            slB2 = (lane < rB2) ? (int)colsrc[iB2 + lane] : 0;
        }
        chunk_math32(qA, qd2A, rA, es, accA);
        chunk_math32(qB, qd2B, rB, es, accB);
        if (!more) break;
        iA = iA2; iB = iB2; rA = rA2; rB = rB2; slA = slA2; slB = slB2;
    }
}

// ---------------- gather + reduce, layers 0..4 (3 output cols), 2 nodes/wave ----------------
__global__ __launch_bounds__(256, 4) void k_gather3(
    const __half* __restrict__ qs, const __half* __restrict__ qd,
    const int* __restrict__ rowstart, const ushort_t* __restrict__ colsrc,
    const float* __restrict__ W2l, const float* __restrict__ b2l,
    float* __restrict__ pnext, float* __restrict__ gsum_l) {
    __shared__ float w2c[3][64];
    __shared__ float b2c[3];
    __shared__ float part[4][8];
    int tid = threadIdx.x;
    if (tid < 192) {
        int cj = tid >> 6;
        int col = (cj == 0) ? 0 : ((cj == 1) ? 1 : 14);
        w2c[cj][tid & 63] = W2l[(tid & 63) * 64 + col];
    }
    if (tid < 3) b2c[tid] = b2l[(tid == 0) ? 0 : ((tid == 1) ? 1 : 14)];
    __syncthreads();

    int w = tid >> 6, lane = tid & 63;
    int es = lane >> 3, cg = lane & 7;
    unsigned int cg16 = (unsigned int)(cg << 4);
    int v0 = (blockIdx.x * 4 + w) * 2;          // nodes v0, v0+1
    const char* qsb = (const char*)qs;

    uint4 qqA = ((const uint4*)qd)[(size_t)v0 * 8 + cg];
    uint4 qqB = ((const uint4*)qd)[(size_t)(v0 + 1) * 8 + cg];
    half2v qd2A[4], qd2B[4];
    {
        unsigned int qa[4] = {qqA.x, qqA.y, qqA.z, qqA.w};
        unsigned int qb[4] = {qqB.x, qqB.y, qqB.z, qqB.w};
#pragma unroll
        for (int d = 0; d < 4; ++d) { qd2A[d] = bitcast_h2(qa[d]); qd2B[d] = bitcast_h2(qb[d]); }
    }

    float accA[8] = {0, 0, 0, 0, 0, 0, 0, 0};
    float accB[8] = {0, 0, 0, 0, 0, 0, 0, 0};
    int s0 = rowstart[v0], e0 = rowstart[v0 + 1], e1 = rowstart[v0 + 2];
    if (es == 0) {  // self loops
        accum8f(qsb, ((unsigned int)(v0 << 7)) | cg16, qd2A, accA);
        accum8f(qsb, ((unsigned int)((v0 + 1) << 7)) | cg16, qd2B, accB);
    }
    pair_edge_loop(qsb, colsrc, s0, e0, e0, e1, lane, es, cg16, qd2A, qd2B, accA, accB);

    // project unfolded partials through the 3 W2 columns, fold all 6 strides
    float degA = (float)(e0 - s0 + 1);
    float degB = (float)(e1 - e0 + 1);
#pragma unroll
    for (int j = 0; j < 3; ++j) {
        float tA = 0.f, tB = 0.f;
#pragma unroll
        for (int k = 0; k < 8; ++k) {
            float wv = w2c[j][cg * 8 + k];
            tA += accA[k] * wv;
            tB += accB[k] * wv;
        }
        tA += __shfl_xor(tA, 1);  tB += __shfl_xor(tB, 1);
        tA += __shfl_xor(tA, 2);  tB += __shfl_xor(tB, 2);
        tA += __shfl_xor(tA, 4);  tB += __shfl_xor(tB, 4);
        tA += __shfl_xor(tA, 8);  tB += __shfl_xor(tB, 8);
        tA += __shfl_xor(tA, 16); tB += __shfl_xor(tB, 16);
        tA += __shfl_xor(tA, 32); tB += __shfl_xor(tB, 32);
        if (lane == 0) {
            float valA = tA + degA * b2c[j];
            float valB = tB + degB * b2c[j];
            pnext[v0 * 3 + j] = valA;
            pnext[(v0 + 1) * 3 + j] = valB;
            part[w][j] = valA + valB;
            part[w][3 + j] = valA * valA + valB * valB;
        }
    }
    __syncthreads();
    if (tid < 6) {
        float ssum = part[0][tid] + part[1][tid] + part[2][tid] + part[3][tid];
        atomicAdd(&gsum_l[(blockIdx.x & (NSLOT - 1)) * 8 + tid], ssum);
    }
}

// ---------------- gather + full 64-col matmul, layer 5, 2 nodes/wave ----------------
__global__ __launch_bounds__(256, 4) void k_gather_full(
    const __half* __restrict__ qs, const __half* __restrict__ qd,
    const int* __restrict__ rowstart, const ushort_t* __restrict__ colsrc,
    const float* __restrict__ W2l, const float* __restrict__ b2l,
    float* __restrict__ out) {
    __shared__ float lds[4][2][64];
    int tid = threadIdx.x;
    int w = tid >> 6, lane = tid & 63;
    int es = lane >> 3, cg = lane & 7;
    unsigned int cg16 = (unsigned int)(cg << 4);
    int v0 = (blockIdx.x * 4 + w) * 2;
    const char* qsb = (const char*)qs;

    uint4 qqA = ((const uint4*)qd)[(size_t)v0 * 8 + cg];
    uint4 qqB = ((const uint4*)qd)[(size_t)(v0 + 1) * 8 + cg];
    half2v qd2A[4], qd2B[4];
    {
        unsigned int qa[4] = {qqA.x, qqA.y, qqA.z, qqA.w};
        unsigned int qb[4] = {qqB.x, qqB.y, qqB.z, qqB.w};
#pragma unroll
        for (int d = 0; d < 4; ++d) { qd2A[d] = bitcast_h2(qa[d]); qd2B[d] = bitcast_h2(qb[d]); }
    }

    float accA[8] = {0, 0, 0, 0, 0, 0, 0, 0};
    float accB[8] = {0, 0, 0, 0, 0, 0, 0, 0};
    int s0 = rowstart[v0], e0 = rowstart[v0 + 1], e1 = rowstart[v0 + 2];
    if (es == 0) {
        accum8f(qsb, ((unsigned int)(v0 << 7)) | cg16, qd2A, accA);
        accum8f(qsb, ((unsigned int)((v0 + 1) << 7)) | cg16, qd2B, accB);
    }
    pair_edge_loop(qsb, colsrc, s0, e0, e0, e1, lane, es, cg16, qd2A, qd2B, accA, accB);

#pragma unroll
    for (int k = 0; k < 8; ++k) {
        accA[k] += __shfl_xor(accA[k], 8);
        accA[k] += __shfl_xor(accA[k], 16);
        accA[k] += __shfl_xor(accA[k], 32);
        accB[k] += __shfl_xor(accB[k], 8);
        accB[k] += __shfl_xor(accB[k], 16);
        accB[k] += __shfl_xor(accB[k], 32);
    }
    if (es == 0) {
#pragma unroll
        for (int k = 0; k < 8; ++k) {
            lds[w][0][cg * 8 + k] = accA[k];
            lds[w][1][cg * 8 + k] = accB[k];
        }
    }
    __syncthreads();
    float degA = (float)(e0 - s0 + 1);
    float degB = (float)(e1 - e0 + 1);
    float bl = b2l[lane];
    float sumA = degA * bl;
    float sumB = degB * bl;
    for (int k = 0; k < 64; ++k) {
        float wv = W2l[k * 64 + lane];
        sumA += lds[w][0][k] * wv;
        sumB += lds[w][1][k] * wv;
    }
    out[(size_t)v0 * 64 + lane] = sumA;
    out[(size_t)(v0 + 1) * 64 + lane] = sumB;
}

// ---------------- launch ----------------

static inline size_t align_up(size_t x) { return (x + 255) & ~(size_t)255; }

extern "C" void kernel_launch(void* const* d_in, const int* in_sizes, int n_in,
                              void* d_out, int out_size, void* d_ws, size_t ws_size,
                              hipStream_t stream) {
    const float* x     = (const float*)d_in[0];
    const int*   ei    = (const int*)d_in[1];
    const float* W1    = (const float*)d_in[2];
    const float* b1    = (const float*)d_in[3];
    const float* W2    = (const float*)d_in[4];
    const float* b2    = (const float*)d_in[5];
    const float* gamma = (const float*)d_in[6];
    const float* beta  = (const float*)d_in[7];
    float* out = (float*)d_out;
    const int E = in_sizes[1] / 2;           // 1,600,000
    const int* src = ei;
    const int* dst = ei + E;

    const int nchunk = (E + CHUNK - 1) / CHUNK;     // 391
    const int nscan  = NBKT * nchunk;
    const int nsb    = (nscan + 255) / 256;

    // workspace carve
    char* base = (char*)d_ws;
    size_t off = 0;
    __half* qs = (__half*)(base + off);     off = align_up(off + (size_t)NN * 64 * 2);
    __half* qd = (__half*)(base + off);     off = align_up(off + (size_t)NN * 64 * 2);
    float* pA = (float*)(base + off);       off = align_up(off + (size_t)NN * 3 * 4);
    float* pB = (float*)(base + off);       off = align_up(off + (size_t)NN * 3 * 4);
    int* rowstart = (int*)(base + off);     off = align_up(off + (size_t)(NN + 1) * 4);
    ushort_t* colsrc = (ushort_t*)(base + off); off = align_up(off + (size_t)E * 2);
    int* ebuf     = (int*)(base + off);     off = align_up(off + (size_t)E * 4);
    int* hist     = (int*)(base + off);     off = align_up(off + (size_t)nscan * 4);
    int* offsT    = (int*)(base + off);     off = align_up(off + (size_t)nscan * 4);
    int* presum   = (int*)(base + off);     off = align_up(off + (size_t)nscan * 4);
    int* bsum     = (int*)(base + off);     off = align_up(off + (size_t)nsb * 4);
    float* gsumsp = (float*)(base + off);   off = align_up(off + (size_t)5 * NSLOT * 8 * 4);
    (void)ws_size; (void)n_in; (void)out_size;

    // CSR build: two-stage counting sort, no hot-line atomics (also zeros gsumsp)
    k_hist1<<<nchunk, 256, 0, stream>>>(dst, E, nchunk, hist, gsumsp);
    k_scanA<<<nsb, 256, 0, stream>>>(hist, nscan, presum, bsum);
    k_scanC<<<nsb, 256, 0, stream>>>(presum, hist, bsum, nscan, nchunk, offsT);
    k_scatter1<<<nchunk, 256, 0, stream>>>(src, dst, E, offsT, ebuf);
    k_bucket_csr<<<NBKT, 256, 0, stream>>>(ebuf, offsT, E, rowstart, colsrc);

    float* pc = pA;
    float* pn = pB;
    for (int l = 0; l < 6; ++l) {
        const float* pin = (l == 0) ? x : pc;
        int pstride = (l == 0) ? 16 : 3;
        int c0 = 0, c1 = 1, c2 = (l == 0) ? 14 : 2;
        const float* gsum_prev = (l == 0) ? gsumsp : gsumsp + (size_t)(l - 1) * NSLOT * 8;
        const float* gamma_prev = (l == 0) ? gamma : gamma + (size_t)(l - 1) * 64;
        const float* beta_prev  = (l == 0) ? beta  : beta  + (size_t)(l - 1) * 64;
        k_q<<<NQBLK8, 256, 0, stream>>>(pin, pstride, c0, c1, c2,
                                        W1 + (size_t)l * 6 * 64, b1 + (size_t)l * 64,
                                        gsum_prev, gamma_prev, beta_prev,
                                        (l > 0) ? 1 : 0, qs, qd);
        if (l < 5) {
            k_gather3<<<NGBLK2, 256, 0, stream>>>(qs, qd, rowstart, colsrc,
                                                  W2 + (size_t)l * 64 * 64, b2 + (size_t)l * 64,
                                                  pn, gsumsp + (size_t)l * NSLOT * 8);
            float* tmp = pc; pc = pn; pn = tmp;
        } else {
            k_gather_full<<<NGBLK2, 256, 0, stream>>>(qs, qd, rowstart, colsrc,
                                                      W2 + (size_t)5 * 64 * 64, b2 + (size_t)5 * 64,
                                                      out);
        }
    }
}

// Round 7
// 395.083 us; speedup vs baseline: 1.5263x; 1.0240x over previous
//
#include <hip/hip_runtime.h>
#include <hip/hip_fp16.h>
#include <cstdint>

#define NN 50000
#define NQBLK8 1563             // k_q blocks: NN*8/256 rounded up
#define NGBLK4 3125             // gather blocks: 16 nodes/block (4 per wave)
#define EPSV 1e-5f

// bucket sort params
#define NPB 128                 // nodes per bucket
#define BSH 7                   // log2(NPB)
#define NBKT 391                // ceil(NN/NPB)
#define CHUNK 4096              // edges per stage-1 block
#define EPT 16                  // edges per thread (CHUNK/256)
#define LDSE 6144               // per-bucket LDS edge capacity

// BN partial-sum spreading: 128 slots x 8 floats per layer (64 cache lines).
// R9/R10: hot-line atomics cost ~120us; spread over 64 lines -> negligible.
#define NSLOT 128

typedef unsigned short ushort_t;
typedef _Float16 half2v __attribute__((ext_vector_type(2)));

// ---------------- stage 1: per-chunk bucket histogram (+ zero BN slots) ----------------
__global__ __launch_bounds__(256) void k_hist1(const int* __restrict__ dst, int E, int nchunk,
                                               int* __restrict__ hist, float* __restrict__ gsumsp) {
    __shared__ int cnt[NBKT];
    int t = threadIdx.x, blk = blockIdx.x;
    if (blk == 0) {
        for (int z = t; z < 5 * NSLOT * 8; z += 256) gsumsp[z] = 0.f;
    }
    for (int b = t; b < NBKT; b += 256) cnt[b] = 0;
    __syncthreads();
    int base = blk * CHUNK;
#pragma unroll
    for (int k = 0; k < EPT; ++k) {
        int e = base + k * 256 + t;
        if (e < E) atomicAdd(&cnt[dst[e] >> BSH], 1);
    }
    __syncthreads();
    for (int b = t; b < NBKT; b += 256) hist[(size_t)b * nchunk + blk] = cnt[b];
}

// ---------------- hierarchical exclusive scan (A: per-block, C: fused apply) ----------------
__global__ __launch_bounds__(256) void k_scanA(const int* __restrict__ in, int n,
                                               int* __restrict__ presum, int* __restrict__ blocksum) {
    __shared__ int lds[256];
    int t = threadIdx.x, g = blockIdx.x * 256 + t;
    int v = (g < n) ? in[g] : 0;
    lds[t] = v;
    __syncthreads();
    for (int off = 1; off < 256; off <<= 1) {
        int x = (t >= off) ? lds[t - off] : 0;
        __syncthreads();
        lds[t] += x;
        __syncthreads();
    }
    if (g < n) presum[g] = lds[t];
    if (t == 255) blocksum[blockIdx.x] = lds[255];
}

// fused scanB+scanC: each block computes its own carry (sum of blocksum[0..blk))
__global__ __launch_bounds__(256) void k_scanC(const int* __restrict__ presum,
                                               const int* __restrict__ hist,
                                               const int* __restrict__ blocksum,
                                               int n, int nchunk, int* __restrict__ offsT) {
    __shared__ int lds[256];
    int t = threadIdx.x, myblk = blockIdx.x;
    int acc = 0;
    for (int i = t; i < myblk; i += 256) acc += blocksum[i];
    lds[t] = acc;
    __syncthreads();
    for (int off = 128; off > 0; off >>= 1) {
        if (t < off) lds[t] += lds[t + off];
        __syncthreads();
    }
    int boff = lds[0];
    int g = myblk * 256 + t;
    if (g < n) {
        int val = presum[g] - hist[g] + boff;
        int b = g / nchunk;
        int c = g - b * nchunk;
        offsT[(size_t)c * NBKT + b] = val;
    }
}

// ---------------- stage 1: partition edges into buckets ----------------
__global__ __launch_bounds__(256) void k_scatter1(const int* __restrict__ src,
                                                  const int* __restrict__ dst, int E,
                                                  const int* __restrict__ offsT,
                                                  int* __restrict__ ebuf) {
    __shared__ int pos[NBKT];
    int t = threadIdx.x, blk = blockIdx.x;
    for (int b = t; b < NBKT; b += 256) pos[b] = offsT[(size_t)blk * NBKT + b];
    __syncthreads();
    int base = blk * CHUNK;
#pragma unroll
    for (int k = 0; k < EPT; ++k) {
        int e = base + k * 256 + t;
        if (e < E) {
            int d = dst[e];
            int b = d >> BSH;
            int p = atomicAdd(&pos[b], 1);
            ebuf[p] = ((d & (NPB - 1)) << 16) | src[e];
        }
    }
}

// ---------------- stage 2: per-bucket CSR ----------------
__global__ __launch_bounds__(256) void k_bucket_csr(const int* __restrict__ ebuf,
                                                    const int* __restrict__ offsT, int E,
                                                    int* __restrict__ rowstart,
                                                    ushort_t* __restrict__ colsrc) {
    __shared__ int cnt[NPB];
    __shared__ int s[NPB];
    __shared__ int pos2[NPB];
    __shared__ ushort_t lout[LDSE];
    int t = threadIdx.x, b = blockIdx.x;
    int bstart = offsT[b];
    int bend = (b + 1 < NBKT) ? offsT[b + 1] : E;
    int m = bend - bstart;
    if (t < NPB) cnt[t] = 0;
    __syncthreads();
    for (int i = bstart + t; i < bend; i += 256) atomicAdd(&cnt[ebuf[i] >> 16], 1);
    __syncthreads();
    if (t < NPB) s[t] = cnt[t];
    __syncthreads();
    for (int off = 1; off < NPB; off <<= 1) {
        int x = (t < NPB && t >= off) ? s[t - off] : 0;
        __syncthreads();
        if (t < NPB) s[t] += x;
        __syncthreads();
    }
    if (t < NPB) {
        int excl = s[t] - cnt[t];
        int node = b * NPB + t;
        if (node < NN) rowstart[node] = bstart + excl;
        pos2[t] = excl;
    }
    __syncthreads();
    if (m <= LDSE) {
        for (int i = bstart + t; i < bend; i += 256) {
            int v = ebuf[i];
            int p = atomicAdd(&pos2[v >> 16], 1);
            lout[p] = (ushort_t)(v & 0xFFFF);
        }
        __syncthreads();
        for (int i = t; i < m; i += 256) colsrc[bstart + i] = lout[i];
    } else {
        for (int i = bstart + t; i < bend; i += 256) {
            int v = ebuf[i];
            int p = atomicAdd(&pos2[v >> 16], 1);
            colsrc[bstart + p] = (ushort_t)(v & 0xFFFF);
        }
    }
    if (b == NBKT - 1 && t == 0) rowstart[NN] = E;
}

// ---------------- per-layer: node -> (q_s, q_d), BN-finalize fused in-block ----------------
__global__ __launch_bounds__(256) void k_q(
    const float* __restrict__ pin, int pstride, int c0, int c1, int c2,
    const float* __restrict__ W1l, const float* __restrict__ b1l,
    const float* __restrict__ gsum_prev, const float* __restrict__ gamma_l,
    const float* __restrict__ beta_l, int use_bn,
    __half* __restrict__ qs, __half* __restrict__ qd) {
    __shared__ float red[6][8];
    __shared__ float scv[3], shv[3];
    int tid = threadIdx.x;
    if (use_bn) {
        if (tid < 48) {
            int j = tid >> 3, k = tid & 7;
            float s = 0.f;
            for (int slot = k; slot < NSLOT; slot += 8) s += gsum_prev[slot * 8 + j];
            red[j][k] = s;
        }
        __syncthreads();
        if (tid < 3) {
            const int cols[3] = {0, 1, 14};
            float sum = 0.f, sumsq = 0.f;
#pragma unroll
            for (int k2 = 0; k2 < 8; ++k2) { sum += red[tid][k2]; sumsq += red[tid + 3][k2]; }
            float mu = sum / (float)NN;
            float var = sumsq / (float)NN - mu * mu;
            float rs = rsqrtf(var + EPSV);
            float g = gamma_l[cols[tid]];
            scv[tid] = rs * g;
            shv[tid] = beta_l[cols[tid]] - mu * rs * g;
        }
        __syncthreads();
    }
    int idx = blockIdx.x * 256 + tid;
    int v = idx >> 3, g = idx & 7;
    if (v >= NN) return;
    const float* prow = pin + (size_t)v * pstride;
    float p0 = prow[c0], p1 = prow[c1], p2 = prow[c2];
    if (use_bn) {
        p0 = fmaxf(0.f, p0 * scv[0] + shv[0]);
        p1 = fmaxf(0.f, p1 * scv[1] + shv[1]);
        p2 = fmaxf(0.f, p2 * scv[2] + shv[2]);
    }
    unsigned int us[4], ud[4];
#pragma unroll
    for (int pr = 0; pr < 4; ++pr) {
        int c = (g << 3) + (pr << 1);
        float w0a = W1l[c], w1a = W1l[64 + c], w2a = W1l[128 + c];
        float qsa = p0 * w0a + p1 * w1a + p2 * w2a;
        float qda = p0 * (W1l[192 + c] - w0a) + p1 * (W1l[256 + c] - w1a)
                  + p2 * (W1l[320 + c] - w2a) + b1l[c];
        int c1i = c + 1;
        float w0b = W1l[c1i], w1b = W1l[64 + c1i], w2b = W1l[128 + c1i];
        float qsb = p0 * w0b + p1 * w1b + p2 * w2b;
        float qdb = p0 * (W1l[192 + c1i] - w0b) + p1 * (W1l[256 + c1i] - w1b)
                  + p2 * (W1l[320 + c1i] - w2b) + b1l[c1i];
        us[pr] = (unsigned int)__half_as_ushort(__float2half(qsa))
               | ((unsigned int)__half_as_ushort(__float2half(qsb)) << 16);
        ud[pr] = (unsigned int)__half_as_ushort(__float2half(qda))
               | ((unsigned int)__half_as_ushort(__float2half(qdb)) << 16);
    }
    uint4 vs = {us[0], us[1], us[2], us[3]};
    uint4 vd = {ud[0], ud[1], ud[2], ud[3]};
    ((uint4*)qs)[(size_t)v * 8 + g] = vs;
    ((uint4*)qd)[(size_t)v * 8 + g] = vd;
}

// ---------------- edge accumulation helpers ----------------
// R9: no per-load branches; masked slots load row 0. R13: no device fences.
// R18/R20: FOUR nodes per wave, 16-slot chunks — one colsrc load covers all
// 4 nodes (lane = node*16 + slot), 8 gather loads in flight per iteration.
// R19: next iteration's colsrc prefetched before math.
__device__ __forceinline__ half2v bitcast_h2(unsigned int u) {
    union { unsigned int u; half2v h; } cvt;
    cvt.u = u;
    return cvt.h;
}

__device__ __forceinline__ void accum8f(const char* __restrict__ qsb, unsigned int byteoff,
                                        const half2v qd2[4], float acc[8]) {
    uint4 q = *reinterpret_cast<const uint4*>(qsb + byteoff);
    unsigned int wd[4] = {q.x, q.y, q.z, q.w};
    const half2v z2 = {(_Float16)0.0f, (_Float16)0.0f};
#pragma unroll
    for (int d = 0; d < 4; ++d) {
        half2v r = bitcast_h2(wd[d]) + qd2[d];
        r = __builtin_elementwise_max(r, z2);
        acc[2 * d]     += (float)r.x;
        acc[2 * d + 1] += (float)r.y;
    }
}

__device__ __forceinline__ void chunk_math16(const uint4 q[2], const half2v qd2[4],
                                             int r, int es, float acc[8]) {
    const half2v z2 = {(_Float16)0.0f, (_Float16)0.0f};
    half2v h[4] = {z2, z2, z2, z2};
#pragma unroll
    for (int k = 0; k < 2; ++k) {
        bool ok = ((k << 3) + es) < r;
        unsigned int wd[4] = {q[k].x, q[k].y, q[k].z, q[k].w};
#pragma unroll
        for (int d = 0; d < 4; ++d) {
            half2v t = bitcast_h2(wd[d]) + qd2[d];      // v_pk_add_f16
            t = __builtin_elementwise_max(t, z2);       // v_pk_max_f16
            h[d] += ok ? t : z2;                        // cndmask + pk_add
        }
    }
#pragma unroll
    for (int d = 0; d < 4; ++d) {
        acc[2 * d]     += (float)h[d].x;
        acc[2 * d + 1] += (float)h[d].y;
    }
}

__device__ __forceinline__ int clamp16(int x) { return x < 16 ? (x < 0 ? 0 : x) : 16; }

// quad loop: nodes 0..3 with CSR ranges [i_n, e_n)
__device__ __forceinline__ void quad_edge_loop(const char* __restrict__ qsb,
                                               const ushort_t* __restrict__ colsrc,
                                               int i0, int e0, int i1, int e1,
                                               int i2, int e2, int i3, int e3,
                                               int lane, int es, unsigned int cg16,
                                               const half2v qd2a[4], const half2v qd2b[4],
                                               const half2v qd2c[4], const half2v qd2d[4],
                                               float accA[8], float accB[8],
                                               float accC[8], float accD[8]) {
    int r0 = clamp16(e0 - i0), r1 = clamp16(e1 - i1);
    int r2 = clamp16(e2 - i2), r3 = clamp16(e3 - i3);
    if ((r0 | r1 | r2 | r3) == 0) return;
    int g = lane >> 4, o = lane & 15;
    int isel = (g == 0) ? i0 : (g == 1) ? i1 : (g == 2) ? i2 : i3;
    int rsel = (g == 0) ? r0 : (g == 1) ? r1 : (g == 2) ? r2 : r3;
    int sl = (o < rsel) ? (int)colsrc[isel + o] : 0;
    while (true) {
        uint4 qA[2], qB[2], qC[2], qD[2];
#pragma unroll
        for (int k = 0; k < 2; ++k) {
            int s = __shfl(sl, 0 * 16 + (k << 3) + es);
            qA[k] = *reinterpret_cast<const uint4*>(qsb + (((unsigned int)(s << 7)) | cg16));
        }
#pragma unroll
        for (int k = 0; k < 2; ++k) {
            int s = __shfl(sl, 1 * 16 + (k << 3) + es);
            qB[k] = *reinterpret_cast<const uint4*>(qsb + (((unsigned int)(s << 7)) | cg16));
        }
#pragma unroll
        for (int k = 0; k < 2; ++k) {
            int s = __shfl(sl, 2 * 16 + (k << 3) + es);
            qC[k] = *reinterpret_cast<const uint4*>(qsb + (((unsigned int)(s << 7)) | cg16));
        }
#pragma unroll
        for (int k = 0; k < 2; ++k) {
            int s = __shfl(sl, 3 * 16 + (k << 3) + es);
            qD[k] = *reinterpret_cast<const uint4*>(qsb + (((unsigned int)(s << 7)) | cg16));
        }
        int j0 = i0 + r0, j1 = i1 + r1, j2 = i2 + r2, j3 = i3 + r3;
        int n0 = clamp16(e0 - j0), n1 = clamp16(e1 - j1);
        int n2 = clamp16(e2 - j2), n3 = clamp16(e3 - j3);
        bool more = (n0 | n1 | n2 | n3) != 0;
        int sl2 = 0;
        if (more) {     // wave-uniform; prefetch next colsrc words before math
            int isel2 = (g == 0) ? j0 : (g == 1) ? j1 : (g == 2) ? j2 : j3;
            int rsel2 = (g == 0) ? n0 : (g == 1) ? n1 : (g == 2) ? n2 : n3;
            sl2 = (o < rsel2) ? (int)colsrc[isel2 + o] : 0;
        }
        chunk_math16(qA, qd2a, r0, es, accA);
        chunk_math16(qB, qd2b, r1, es, accB);
        chunk_math16(qC, qd2c, r2, es, accC);
        chunk_math16(qD, qd2d, r3, es, accD);
        if (!more) break;
        i0 = j0; i1 = j1; i2 = j2; i3 = j3;
        r0 = n0; r1 = n1; r2 = n2; r3 = n3;
        sl = sl2;
    }
}

// ---------------- gather + reduce, layers 0..4 (3 output cols), 4 nodes/wave ----------------
__global__ __launch_bounds__(256) void k_gather3(
    const __half* __restrict__ qs, const __half* __restrict__ qd,
    const int* __restrict__ rowstart, const ushort_t* __restrict__ colsrc,
    const float* __restrict__ W2l, const float* __restrict__ b2l,
    float* __restrict__ pnext, float* __restrict__ gsum_l) {
    __shared__ float w2c[3][64];
    __shared__ float b2c[3];
    __shared__ float part[4][8];
    int tid = threadIdx.x;
    if (tid < 192) {
        int cj = tid >> 6;
        int col = (cj == 0) ? 0 : ((cj == 1) ? 1 : 14);
        w2c[cj][tid & 63] = W2l[(tid & 63) * 64 + col];
    }
    if (tid < 3) b2c[tid] = b2l[(tid == 0) ? 0 : ((tid == 1) ? 1 : 14)];
    __syncthreads();

    int w = tid >> 6, lane = tid & 63;
    int es = lane >> 3, cg = lane & 7;
    unsigned int cg16 = (unsigned int)(cg << 4);
    int v0 = (blockIdx.x * 4 + w) * 4;          // nodes v0..v0+3
    const char* qsb = (const char*)qs;

    half2v qd2a[4], qd2b[4], qd2c[4], qd2d[4];
    {
        uint4 qA = ((const uint4*)qd)[(size_t)v0 * 8 + cg];
        uint4 qB = ((const uint4*)qd)[(size_t)(v0 + 1) * 8 + cg];
        uint4 qC = ((const uint4*)qd)[(size_t)(v0 + 2) * 8 + cg];
        uint4 qD = ((const uint4*)qd)[(size_t)(v0 + 3) * 8 + cg];
        unsigned int ua[4] = {qA.x, qA.y, qA.z, qA.w};
        unsigned int ub[4] = {qB.x, qB.y, qB.z, qB.w};
        unsigned int uc[4] = {qC.x, qC.y, qC.z, qC.w};
        unsigned int ud[4] = {qD.x, qD.y, qD.z, qD.w};
#pragma unroll
        for (int d = 0; d < 4; ++d) {
            qd2a[d] = bitcast_h2(ua[d]); qd2b[d] = bitcast_h2(ub[d]);
            qd2c[d] = bitcast_h2(uc[d]); qd2d[d] = bitcast_h2(ud[d]);
        }
    }

    float accA[8] = {0,0,0,0,0,0,0,0};
    float accB[8] = {0,0,0,0,0,0,0,0};
    float accC[8] = {0,0,0,0,0,0,0,0};
    float accD[8] = {0,0,0,0,0,0,0,0};
    int rs0 = rowstart[v0], rs1 = rowstart[v0 + 1], rs2 = rowstart[v0 + 2];
    int rs3 = rowstart[v0 + 3], rs4 = rowstart[v0 + 4];
    if (es == 0) {  // self loops (8 lanes, 4 sequential rows)
        accum8f(qsb, ((unsigned int)(v0 << 7)) | cg16, qd2a, accA);
        accum8f(qsb, ((unsigned int)((v0 + 1) << 7)) | cg16, qd2b, accB);
        accum8f(qsb, ((unsigned int)((v0 + 2) << 7)) | cg16, qd2c, accC);
        accum8f(qsb, ((unsigned int)((v0 + 3) << 7)) | cg16, qd2d, accD);
    }
    quad_edge_loop(qsb, colsrc, rs0, rs1, rs1, rs2, rs2, rs3, rs3, rs4,
                   lane, es, cg16, qd2a, qd2b, qd2c, qd2d, accA, accB, accC, accD);

    float degA = (float)(rs1 - rs0 + 1);
    float degB = (float)(rs2 - rs1 + 1);
    float degC = (float)(rs3 - rs2 + 1);
    float degD = (float)(rs4 - rs3 + 1);
#pragma unroll
    for (int j = 0; j < 3; ++j) {
        float tA = 0.f, tB = 0.f, tC = 0.f, tD = 0.f;
#pragma unroll
        for (int k = 0; k < 8; ++k) {
            float wv = w2c[j][cg * 8 + k];
            tA += accA[k] * wv; tB += accB[k] * wv;
            tC += accC[k] * wv; tD += accD[k] * wv;
        }
#pragma unroll
        for (int st = 1; st <= 32; st <<= 1) {
            tA += __shfl_xor(tA, st); tB += __shfl_xor(tB, st);
            tC += __shfl_xor(tC, st); tD += __shfl_xor(tD, st);
        }
        if (lane == 0) {
            float vA = tA + degA * b2c[j];
            float vB = tB + degB * b2c[j];
            float vC = tC + degC * b2c[j];
            float vD = tD + degD * b2c[j];
            pnext[v0 * 3 + j] = vA;
            pnext[(v0 + 1) * 3 + j] = vB;
            pnext[(v0 + 2) * 3 + j] = vC;
            pnext[(v0 + 3) * 3 + j] = vD;
            part[w][j] = vA + vB + vC + vD;
            part[w][3 + j] = vA * vA + vB * vB + vC * vC + vD * vD;
        }
    }
    __syncthreads();
    if (tid < 6) {
        float ssum = part[0][tid] + part[1][tid] + part[2][tid] + part[3][tid];
        atomicAdd(&gsum_l[(blockIdx.x & (NSLOT - 1)) * 8 + tid], ssum);
    }
}

// ---------------- gather + full 64-col matmul, layer 5, 4 nodes/wave ----------------
__global__ __launch_bounds__(256) void k_gather_full(
    const __half* __restrict__ qs, const __half* __restrict__ qd,
    const int* __restrict__ rowstart, const ushort_t* __restrict__ colsrc,
    const float* __restrict__ W2l, const float* __restrict__ b2l,
    float* __restrict__ out) {
    __shared__ float lds[4][4][64];
    int tid = threadIdx.x;
    int w = tid >> 6, lane = tid & 63;
    int es = lane >> 3, cg = lane & 7;
    unsigned int cg16 = (unsigned int)(cg << 4);
    int v0 = (blockIdx.x * 4 + w) * 4;
    const char* qsb = (const char*)qs;

    half2v qd2a[4], qd2b[4], qd2c[4], qd2d[4];
    {
        uint4 qA = ((const uint4*)qd)[(size_t)v0 * 8 + cg];
        uint4 qB = ((const uint4*)qd)[(size_t)(v0 + 1) * 8 + cg];
        uint4 qC = ((const uint4*)qd)[(size_t)(v0 + 2) * 8 + cg];
        uint4 qD = ((const uint4*)qd)[(size_t)(v0 + 3) * 8 + cg];
        unsigned int ua[4] = {qA.x, qA.y, qA.z, qA.w};
        unsigned int ub[4] = {qB.x, qB.y, qB.z, qB.w};
        unsigned int uc[4] = {qC.x, qC.y, qC.z, qC.w};
        unsigned int ud[4] = {qD.x, qD.y, qD.z, qD.w};
#pragma unroll
        for (int d = 0; d < 4; ++d) {
            qd2a[d] = bitcast_h2(ua[d]); qd2b[d] = bitcast_h2(ub[d]);
            qd2c[d] = bitcast_h2(uc[d]); qd2d[d] = bitcast_h2(ud[d]);
        }
    }

    float accA[8] = {0,0,0,0,0,0,0,0};
    float accB[8] = {0,0,0,0,0,0,0,0};
    float accC[8] = {0,0,0,0,0,0,0,0};
    float accD[8] = {0,0,0,0,0,0,0,0};
    int rs0 = rowstart[v0], rs1 = rowstart[v0 + 1], rs2 = rowstart[v0 + 2];
    int rs3 = rowstart[v0 + 3], rs4 = rowstart[v0 + 4];
    if (es == 0) {
        accum8f(qsb, ((unsigned int)(v0 << 7)) | cg16, qd2a, accA);
        accum8f(qsb, ((unsigned int)((v0 + 1) << 7)) | cg16, qd2b, accB);
        accum8f(qsb, ((unsigned int)((v0 + 2) << 7)) | cg16, qd2c, accC);
        accum8f(qsb, ((unsigned int)((v0 + 3) << 7)) | cg16, qd2d, accD);
    }
    quad_edge_loop(qsb, colsrc, rs0, rs1, rs1, rs2, rs2, rs3, rs3, rs4,
                   lane, es, cg16, qd2a, qd2b, qd2c, qd2d, accA, accB, accC, accD);

#pragma unroll
    for (int k = 0; k < 8; ++k) {
#pragma unroll
        for (int st = 8; st <= 32; st <<= 1) {
            accA[k] += __shfl_xor(accA[k], st);
            accB[k] += __shfl_xor(accB[k], st);
            accC[k] += __shfl_xor(accC[k], st);
            accD[k] += __shfl_xor(accD[k], st);
        }
    }
    if (es == 0) {
#pragma unroll
        for (int k = 0; k < 8; ++k) {
            lds[w][0][cg * 8 + k] = accA[k];
            lds[w][1][cg * 8 + k] = accB[k];
            lds[w][2][cg * 8 + k] = accC[k];
            lds[w][3][cg * 8 + k] = accD[k];
        }
    }
    __syncthreads();
    float bl = b2l[lane];
    float sumA = (float)(rs1 - rs0 + 1) * bl;
    float sumB = (float)(rs2 - rs1 + 1) * bl;
    float sumC = (float)(rs3 - rs2 + 1) * bl;
    float sumD = (float)(rs4 - rs3 + 1) * bl;
    for (int k = 0; k < 64; ++k) {
        float wv = W2l[k * 64 + lane];
        sumA += lds[w][0][k] * wv;
        sumB += lds[w][1][k] * wv;
        sumC += lds[w][2][k] * wv;
        sumD += lds[w][3][k] * wv;
    }
    out[(size_t)v0 * 64 + lane] = sumA;
    out[(size_t)(v0 + 1) * 64 + lane] = sumB;
    out[(size_t)(v0 + 2) * 64 + lane] = sumC;
    out[(size_t)(v0 + 3) * 64 + lane] = sumD;
}

// ---------------- launch ----------------

static inline size_t align_up(size_t x) { return (x + 255) & ~(size_t)255; }

extern "C" void kernel_launch(void* const* d_in, const int* in_sizes, int n_in,
                              void* d_out, int out_size, void* d_ws, size_t ws_size,
                              hipStream_t stream) {
    const float* x     = (const float*)d_in[0];
    const int*   ei    = (const int*)d_in[1];
    const float* W1    = (const float*)d_in[2];
    const float* b1    = (const float*)d_in[3];
    const float* W2    = (const float*)d_in[4];
    const float* b2    = (const float*)d_in[5];
    const float* gamma = (const float*)d_in[6];
    const float* beta  = (const float*)d_in[7];
    float* out = (float*)d_out;
    const int E = in_sizes[1] / 2;           // 1,600,000
    const int* src = ei;
    const int* dst = ei + E;

    const int nchunk = (E + CHUNK - 1) / CHUNK;     // 391
    const int nscan  = NBKT * nchunk;
    const int nsb    = (nscan + 255) / 256;

    // workspace carve
    char* base = (char*)d_ws;
    size_t off = 0;
    __half* qs = (__half*)(base + off);     off = align_up(off + (size_t)NN * 64 * 2);
    __half* qd = (__half*)(base + off);     off = align_up(off + (size_t)NN * 64 * 2);
    float* pA = (float*)(base + off);       off = align_up(off + (size_t)NN * 3 * 4);
    float* pB = (float*)(base + off);       off = align_up(off + (size_t)NN * 3 * 4);
    int* rowstart = (int*)(base + off);     off = align_up(off + (size_t)(NN + 1) * 4);
    ushort_t* colsrc = (ushort_t*)(base + off); off = align_up(off + (size_t)E * 2);
    int* ebuf     = (int*)(base + off);     off = align_up(off + (size_t)E * 4);
    int* hist     = (int*)(base + off);     off = align_up(off + (size_t)nscan * 4);
    int* offsT    = (int*)(base + off);     off = align_up(off + (size_t)nscan * 4);
    int* presum   = (int*)(base + off);     off = align_up(off + (size_t)nscan * 4);
    int* bsum     = (int*)(base + off);     off = align_up(off + (size_t)nsb * 4);
    float* gsumsp = (float*)(base + off);   off = align_up(off + (size_t)5 * NSLOT * 8 * 4);
    (void)ws_size; (void)n_in; (void)out_size;

    // CSR build: two-stage counting sort, no hot-line atomics (also zeros gsumsp)
    k_hist1<<<nchunk, 256, 0, stream>>>(dst, E, nchunk, hist, gsumsp);
    k_scanA<<<nsb, 256, 0, stream>>>(hist, nscan, presum, bsum);
    k_scanC<<<nsb, 256, 0, stream>>>(presum, hist, bsum, nscan, nchunk, offsT);
    k_scatter1<<<nchunk, 256, 0, stream>>>(src, dst, E, offsT, ebuf);
    k_bucket_csr<<<NBKT, 256, 0, stream>>>(ebuf, offsT, E, rowstart, colsrc);

    float* pc = pA;
    float* pn = pB;
    for (int l = 0; l < 6; ++l) {
        const float* pin = (l == 0) ? x : pc;
        int pstride = (l == 0) ? 16 : 3;
        int c0 = 0, c1 = 1, c2 = (l == 0) ? 14 : 2;
        const float* gsum_prev = (l == 0) ? gsumsp : gsumsp + (size_t)(l - 1) * NSLOT * 8;
        const float* gamma_prev = (l == 0) ? gamma : gamma + (size_t)(l - 1) * 64;
        const float* beta_prev  = (l == 0) ? beta  : beta  + (size_t)(l - 1) * 64;
        k_q<<<NQBLK8, 256, 0, stream>>>(pin, pstride, c0, c1, c2,
                                        W1 + (size_t)l * 6 * 64, b1 + (size_t)l * 64,
                                        gsum_prev, gamma_prev, beta_prev,
                                        (l > 0) ? 1 : 0, qs, qd);
        if (l < 5) {
            k_gather3<<<NGBLK4, 256, 0, stream>>>(qs, qd, rowstart, colsrc,
                                                  W2 + (size_t)l * 64 * 64, b2 + (size_t)l * 64,
                                                  pn, gsumsp + (size_t)l * NSLOT * 8);
            float* tmp = pc; pc = pn; pn = tmp;
        } else {
            k_gather_full<<<NGBLK4, 256, 0, stream>>>(qs, qd, rowstart, colsrc,
                                                      W2 + (size_t)5 * 64 * 64, b2 + (size_t)5 * 64,
                                                      out);
        }
    }
}